// Round 14
// baseline (241.695 us; speedup 1.0000x reference)
//
#include <hip/hip_runtime.h>
#include <hip/hip_bf16.h>

typedef __hip_bfloat16 bf16;
typedef short short8 __attribute__((ext_vector_type(8)));  // 8 bf16 (4 VGPRs)
typedef float f32x4 __attribute__((ext_vector_type(4)));

__device__ __forceinline__ float b2f(bf16 v) { return __bfloat162float(v); }

// RNE fp32 -> bf16
__device__ __forceinline__ unsigned short f2bf(float x) {
  unsigned u = __builtin_bit_cast(unsigned, x);
  unsigned r = u + 0x7fffu + ((u >> 16) & 1u);
  return (unsigned short)(r >> 16);
}
__device__ __forceinline__ unsigned pk2(float a, float b) {
  return (unsigned)f2bf(a) | ((unsigned)f2bf(b) << 16);
}
// truncating pack via single v_perm_b32: dst = {a.hi16, b.hi16}
__device__ __forceinline__ unsigned pk2t(float a, float b) {
  return __builtin_amdgcn_perm(__builtin_bit_cast(unsigned, b),
                               __builtin_bit_cast(unsigned, a), 0x07060302u);
}
__device__ __forceinline__ float rd(const void* p, size_t i, int is32) {
  return is32 ? ((const float*)p)[i] : b2f(((const bf16*)p)[i]);
}
__device__ __forceinline__ float blo(unsigned w) {
  return __builtin_bit_cast(float, w << 16);
}
__device__ __forceinline__ float bhi(unsigned w) {
  return __builtin_bit_cast(float, w & 0xffff0000u);
}
// raw v_exp_f32 (scores bounded; no OCML special-casing)
__device__ __forceinline__ float fexp2(float x) {
  return __builtin_amdgcn_exp2f(x);
}
// async global->LDS, 16B per lane; LDS dest wave-uniform base + lane*16
__device__ __forceinline__ void gld_lds16(const void* g, void* l) {
  __builtin_amdgcn_global_load_lds(
      (const __attribute__((address_space(1))) unsigned int*)g,
      (__attribute__((address_space(3))) unsigned int*)l, 16, 0, 0);
}

#define CQ 0.09016844005556022f  // (1/16) * log2(e), folded into q weights

// ---------------------------------------------------------------------------
// dtype detect: flag=1 fp32, flag=0 bf16 (see round-1 notes)
// ---------------------------------------------------------------------------
__global__ void __launch_bounds__(256) detect_kernel(const void* __restrict__ x,
                                                     int* __restrict__ flag) {
  __shared__ int cnt[256];
  const bf16* xb = (const bf16*)x;
  int c = 0;
  for (int i = threadIdx.x; i < 4096; i += 256) {
    float v = fabsf(b2f(xb[2 * i]));
    if (v >= 0.0009765625f && v <= 1024.0f) c++;
  }
  cnt[threadIdx.x] = c;
  __syncthreads();
  for (int off = 128; off > 0; off >>= 1) {
    if (threadIdx.x < off) cnt[threadIdx.x] += cnt[threadIdx.x + off];
    __syncthreads();
  }
  if (threadIdx.x == 0) *flag = (cnt[0] < 2048) ? 1 : 0;
}

// ---------------------------------------------------------------------------
// pre1: fused xt (blocks 0..511, vectorized loads) + gn_stats (blocks 512..575)
// ---------------------------------------------------------------------------
__global__ void __launch_bounds__(256) pre1_kernel(
    const void* __restrict__ x, const void* __restrict__ gn_w,
    const void* __restrict__ gn_b, const int* __restrict__ flag,
    float* __restrict__ scale, float* __restrict__ shift,
    short* __restrict__ xT) {
  __shared__ __align__(16) float F[64][72];
  const int t = threadIdx.x;
  const int is32 = *flag;
  if (blockIdx.x < 512) {
    const int bx = blockIdx.x;
    const int b = bx >> 8, rest = bx & 255;
    const int s0 = (rest >> 2) * 64, c0 = (rest & 3) * 64;
    if (is32) {
      const float* xp = (const float*)x;
#pragma unroll
      for (int k = 0; k < 4; k++) {
        int idx = k * 256 + t, cl = idx >> 4, c4 = idx & 15;
        float4 v = *(const float4*)&xp[(size_t)(b * 256 + c0 + cl) * 4096 + s0 +
                                       c4 * 4];
        *(float4*)&F[cl][c4 * 4] = v;
      }
    } else {
      const bf16* xp = (const bf16*)x;
#pragma unroll
      for (int k = 0; k < 2; k++) {
        int idx = k * 256 + t, cl = idx >> 3, c8 = idx & 7;
        uint4 u = *(const uint4*)&xp[(size_t)(b * 256 + c0 + cl) * 4096 + s0 +
                                     c8 * 8];
        float4 f0, f1;
        f0.x = blo(u.x); f0.y = bhi(u.x); f0.z = blo(u.y); f0.w = bhi(u.y);
        f1.x = blo(u.z); f1.y = bhi(u.z); f1.z = blo(u.w); f1.w = bhi(u.w);
        *(float4*)&F[cl][c8 * 8] = f0;
        *(float4*)&F[cl][c8 * 8 + 4] = f1;
      }
    }
    __syncthreads();
#pragma unroll
    for (int k = 0; k < 8; k++) {
      int idx = k * 256 + t;
      int sl = idx >> 5, c2 = (idx & 31) * 2;
      unsigned u = pk2(F[c2][sl], F[c2 + 1][sl]);
      *(unsigned*)&xT[((size_t)b * 4096 + s0 + sl) * 256 + c0 + c2] = u;
    }
  } else {
    const int idx0 = blockIdx.x - 512;
    const int b = idx0 >> 5, g = idx0 & 31;
    const size_t base = (size_t)(b * 256 + g * 8) * 4096;
    float s = 0.f, ss = 0.f;
    if (is32) {
      const float4* p = (const float4*)((const float*)x + base);
      for (int i = t; i < 8192; i += 256) {
        float4 v = p[i];
        s += (v.x + v.y) + (v.z + v.w);
        ss += v.x * v.x + v.y * v.y + v.z * v.z + v.w * v.w;
      }
    } else {
      const uint4* p = (const uint4*)((const bf16*)x + base);
      for (int i = t; i < 4096; i += 256) {
        uint4 u = p[i];
#pragma unroll
        for (int k = 0; k < 4; k++) {
          unsigned w = (&u.x)[k];
          float lo = blo(w), hi = bhi(w);
          s += lo + hi;
          ss += lo * lo + hi * hi;
        }
      }
    }
    float* rs = &F[0][0];
    float* rq = rs + 256;
    rs[t] = s;
    rq[t] = ss;
    __syncthreads();
    for (int off = 128; off > 0; off >>= 1) {
      if (t < off) {
        rs[t] += rs[t + off];
        rq[t] += rq[t + off];
      }
      __syncthreads();
    }
    if (t < 8) {
      const float inv_n = 1.f / 32768.f;
      float mean = rs[0] * inv_n;
      float var = rq[0] * inv_n - mean * mean;
      float rstd = rsqrtf(var + 1e-5f);
      int c = g * 8 + t;
      float sc = rd(gn_w, c, is32) * rstd;
      scale[b * 256 + c] = sc;
      shift[b * 256 + c] = rd(gn_b, c, is32) - mean * sc;
    }
  }
}

// ---------------------------------------------------------------------------
// pre2: fused prep_w (bx<192) + conv_o (bx>=192, by==0).
// ---------------------------------------------------------------------------
__global__ void __launch_bounds__(256) pre2_kernel(
    const void* __restrict__ qkv_w, const void* __restrict__ o_w,
    const void* __restrict__ o_b, const float* __restrict__ scale,
    const float* __restrict__ shift, const int* __restrict__ flag,
    short* __restrict__ W2, float* __restrict__ bias2, short* __restrict__ owb,
    float* __restrict__ obf) {
  const int is32 = *flag;
  if (blockIdx.x < 192) {
    const int b = blockIdx.y;
    const int o = blockIdx.x * 4 + (threadIdx.x >> 6);
    const int lane = threadIdx.x & 63;
    const float f = (o % 192 < 64) ? CQ : 1.0f;
    float w[4], acc = 0.f;
#pragma unroll
    for (int k = 0; k < 4; k++) {
      int c = lane * 4 + k;
      w[k] = rd(qkv_w, (size_t)o * 256 + c, is32);
      acc += w[k] * shift[b * 256 + c];
      w[k] = w[k] * scale[b * 256 + c] * f;
    }
#pragma unroll
    for (int m = 1; m < 64; m <<= 1) acc += __shfl_xor(acc, m);
    if (lane == 0) bias2[b * 768 + o] = acc * f;
    uint2 u;
    u.x = pk2(w[0], w[1]);
    u.y = pk2(w[2], w[3]);
    *(uint2*)&W2[((size_t)b * 768 + o) * 256 + lane * 4] = u;
  } else if (blockIdx.y == 0) {
    int bx = blockIdx.x - 192;  // 0..63
    int i = (bx * 256 + threadIdx.x) * 4;
    uint2 u;
    u.x = pk2(rd(o_w, i, is32), rd(o_w, i + 1, is32));
    u.y = pk2(rd(o_w, i + 2, is32), rd(o_w, i + 3, is32));
    *(uint2*)&owb[i] = u;
    if (bx == 0) obf[threadIdx.x] = rd(o_b, threadIdx.x, is32);
  }
}

// ---------------------------------------------------------------------------
// QKV MFMA GEMM (r15/r17 version — proven): D[s][o] = xT·W2^T (+bias2).
// Block 128s x 64o, per-kt staging. seg 0 (q): row-major qT. seg 1 (k):
// fragment-major Kf. seg 2 (v): transpose + fragment-major Vf.
// ---------------------------------------------------------------------------
__global__ void __launch_bounds__(256) gemm_qkv_kernel(
    const short* __restrict__ xT, const short* __restrict__ W2,
    const float* __restrict__ bias2, short* __restrict__ qT,
    short* __restrict__ kF, short* __restrict__ vF) {
  __shared__ __align__(16) short lds[128 * 72 + 64 * 72];
  short* At = lds;             // xT tile [128 s][72]
  short* Bt = lds + 128 * 72;  // W2 tile [64 o][72]
  const int t = threadIdx.x;
  const int wave = t >> 6, lane = t & 63;
  const int ln = lane & 15, quad = lane >> 4;
  const int s0 = blockIdx.x * 128, by = blockIdx.y, b = blockIdx.z;
  const int o0 = by * 64;
  const short* xg = xT + ((size_t)b * 4096 + s0) * 256;
  const short* wg = W2 + ((size_t)b * 768 + o0) * 256;

  f32x4 acc[2][4];
#pragma unroll
  for (int mt = 0; mt < 2; mt++)
#pragma unroll
    for (int nt = 0; nt < 4; nt++) {
      f32x4 z = {0.f, 0.f, 0.f, 0.f};
      acc[mt][nt] = z;
    }

  for (int kt = 0; kt < 4; kt++) {
    __syncthreads();
    {
      int r = t >> 1, ch = t & 1;
#pragma unroll
      for (int j = 0; j < 4; j++)
        *(uint4*)&At[r * 72 + ch * 32 + j * 8] =
            *(const uint4*)&xg[(size_t)r * 256 + kt * 64 + ch * 32 + j * 8];
    }
    {
      int r = t >> 2, cq = t & 3;
#pragma unroll
      for (int j = 0; j < 2; j++)
        *(uint4*)&Bt[r * 72 + cq * 16 + j * 8] =
            *(const uint4*)&wg[(size_t)r * 256 + kt * 64 + cq * 16 + j * 8];
    }
    __syncthreads();
#pragma unroll
    for (int kd = 0; kd < 2; kd++) {
      short8 a[2], bb[4];
#pragma unroll
      for (int mt = 0; mt < 2; mt++)
        a[mt] = *(const short8*)&At[(wave * 32 + mt * 16 + ln) * 72 + kd * 32 +
                                    quad * 8];
#pragma unroll
      for (int nt = 0; nt < 4; nt++)
        bb[nt] = *(const short8*)&Bt[(nt * 16 + ln) * 72 + kd * 32 + quad * 8];
#pragma unroll
      for (int mt = 0; mt < 2; mt++)
#pragma unroll
        for (int nt = 0; nt < 4; nt++)
          acc[mt][nt] = __builtin_amdgcn_mfma_f32_16x16x32_bf16(
              a[mt], bb[nt], acc[mt][nt], 0, 0, 0);
    }
  }

  const int h = by / 3, seg = by % 3;
  const size_t bh = (size_t)b * 4 + h;
  __syncthreads();
  if (seg != 2) {
    short* T = At;  // [128 s][72] = [key_local][dh]
#pragma unroll
    for (int mt = 0; mt < 2; mt++)
#pragma unroll
      for (int nt = 0; nt < 4; nt++)
#pragma unroll
        for (int r = 0; r < 4; r++)
          T[(wave * 32 + mt * 16 + quad * 4 + r) * 72 + nt * 16 + ln] =
              (short)f2bf(acc[mt][nt][r] + bias2[b * 768 + o0 + nt * 16 + ln]);
    __syncthreads();
    if (seg == 0) {  // q: row-major
      short* dst = qT + (bh * 4096 + s0) * 64;
      int r = t >> 1, ch = t & 1;
#pragma unroll
      for (int j = 0; j < 2; j++)
        *(uint4*)&dst[r * 64 + ch * 32 + j * 8] =
            *(const uint4*)&T[r * 72 + ch * 32 + j * 8];
    } else {  // k: fragment-major
      short* dstf = kF + bh * 262144;
#pragma unroll
      for (int c = 0; c < 4; c++) {
        int cid = wave * 4 + c;
        int tile = cid >> 1, kd = cid & 1;
        short8 v =
            *(const short8*)&T[(tile * 16 + ln) * 72 + kd * 32 + quad * 8];
        *(short8*)&dstf[(size_t)((s0 / 16 + tile) * 2 + kd) * 512 + lane * 8] =
            v;
      }
    }
  } else {
    short* T2 = At;  // [64 dh][132 key_local]
#pragma unroll
    for (int mt = 0; mt < 2; mt++)
#pragma unroll
      for (int nt = 0; nt < 4; nt++) {
        float bv = bias2[b * 768 + o0 + nt * 16 + ln];
        uint2 u;
        u.x = pk2(acc[mt][nt][0] + bv, acc[mt][nt][1] + bv);
        u.y = pk2(acc[mt][nt][2] + bv, acc[mt][nt][3] + bv);
        *(uint2*)&T2[(nt * 16 + ln) * 132 + wave * 32 + mt * 16 + quad * 4] = u;
      }
    __syncthreads();
    short* dstf = vF + bh * 262144;
#pragma unroll
    for (int c = 0; c < 4; c++) {
      int cid = wave * 4 + c;
      int ktl = cid >> 3, rem = cid & 7, dt = rem >> 1, kc = rem & 1;
      short8 v = *(const short8*)&T2[(dt * 16 + ln) * 132 + ktl * 64 + kc * 32 +
                                     quad * 8];
      *(short8*)&dstf[(size_t)(((s0 / 64 + ktl) * 4 + dt) * 2 + kc) * 512 +
                      lane * 8] = v;
    }
  }
}

// ---------------------------------------------------------------------------
// Flash MFMA v18: v15's EXACT register structure (K reg-dbuf kaA/kaB,
// single va set, per-tq STEP) + V prefetch depth moved to LDS via
// global_load_lds (DMA — zero VGPR cost for in-flight data).
// Post-mortems: v16 (4 reg buffer sets) and v17 (3 sets + wide st) BOTH
// spilled ~100 MB/dispatch of scratch (WRITE_SIZE 8->99/117 MB, flash
// 64.7 -> 114 us): the ~128-VGPR/wave budget at 4 waves/SIMD caps us at
// v15's 3 buffer sets. v18 sidesteps registers entirely for V:
//  - per wave 2 LDS slots of 4 KB; STAGEV(slot, it+2) issues 4x
//    global_load_lds(16B/lane) at the END of step it, consumed by
//    ds_read_b128 at the TOP of step it+2 -> ~1 full STEP (~925 cyc)
//    cover vs v15's ~400 (the measured ~6k cyc/iter exposed-latency gap).
//  - counted s_waitcnt vmcnt(8): steady-state 16 outstanding
//    {stageA4,kA4,stageB4,kB4}; retire oldest 8 = the slot+K about to be
//    consumed. vmcnt(0) at the last step. sched_barrier(0) pins phase
//    boundaries so ds_read/DMA to the same slot can't reorder.
//  - LDS: staging 32 KB aliased with the combine region (each wave's
//    partials land exactly in its own staging bytes; lsum separate 2 KB).
//    Total 34816 B (was 40960), occupancy unchanged.
//  - slot WAR safe: ds_read of slot s completes (lgkmcnt before PV MFMA)
//    before STAGEV(s,.) is issued (pinned after STEP by sched_barrier).
// Output bytes identical to v15.
// ---------------------------------------------------------------------------
__global__ void __launch_bounds__(256, 4) flash_kernel(
    const short* __restrict__ qT, const short* __restrict__ kF,
    const short* __restrict__ vF, short* __restrict__ attT) {
  // loop: Vst[wave][2 slots][2048 shorts] (32 KB)
  // end (aliased): part[w2t][lane][16] f32 (32 KB) + lsum[w2t][lane] (2 KB)
  __shared__ __align__(16) char smem_raw[34816];
  short* Vst = (short*)smem_raw;
  float* part = (float*)smem_raw;
  float* lsum = (float*)(smem_raw + 32768);
  const int t = threadIdx.x;
  const int wave = t >> 6, lane = t & 63;
  const int ln = lane & 15, quad = lane >> 4;
  const int L = blockIdx.x;
  const int bh = L & 7;  // XCD-pinned head stream
  const int b = bh >> 2, h = bh & 3;
  const int q0 = (L >> 3) * 32;

  const short* qg = qT + ((size_t)bh * 4096 + q0) * 64;
  // wave owns key quarter [wave*1024, wave*1024+1024)
  const short* kf = kF + (size_t)bh * 262144 + (size_t)wave * 65536;
  const short* vf = vF + (size_t)bh * 262144 + (size_t)wave * 65536;
  short* Vw = Vst + wave * 4096;  // [slot][dt*512 + lane*8]

  short8 qf[2][2];
#pragma unroll
  for (int tq = 0; tq < 2; tq++)
#pragma unroll
    for (int kd = 0; kd < 2; kd++)
      qf[tq][kd] = *(const short8*)&qg[(tq * 16 + ln) * 64 + kd * 32 + quad * 8];

  f32x4 ot[2][4];
#pragma unroll
  for (int tq = 0; tq < 2; tq++)
#pragma unroll
    for (int dt = 0; dt < 4; dt++) {
      f32x4 z = {0.f, 0.f, 0.f, 0.f};
      ot[tq][dt] = z;
    }
  float lres[2] = {0.f, 0.f};

  // 32-key step it (0..31): K tiles it*2+{0,1}; V tile64 it>>1, kc=it&1
  auto LOADK = [&](short8(&ka)[2][2], int it) {
    const short* kb = kf + (size_t)(it * 2) * 1024;
#pragma unroll
    for (int ct = 0; ct < 2; ct++)
#pragma unroll
      for (int kd = 0; kd < 2; kd++)
        ka[ct][kd] = *(const short8*)&kb[(ct * 2 + kd) * 512 + lane * 8];
  };
  auto STAGEV = [&](int slot, int it) {
    const short* vb = vf + (size_t)(it >> 1) * 4096;
    const int kc = it & 1;
#pragma unroll
    for (int dt = 0; dt < 4; dt++)
      gld_lds16(&vb[(dt * 2 + kc) * 512 + lane * 8],
                &Vw[slot * 2048 + dt * 512]);
  };
  short8 va[4];
  auto READV = [&](int slot) {
#pragma unroll
    for (int dt = 0; dt < 4; dt++)
      va[dt] = *(const short8*)&Vw[slot * 2048 + dt * 512 + lane * 8];
  };

  auto STEP = [&](const short8(&ka)[2][2]) {
#pragma unroll
    for (int tq = 0; tq < 2; tq++) {
      f32x4 st[2];
#pragma unroll
      for (int ct = 0; ct < 2; ct++) {
        f32x4 z = {0.f, 0.f, 0.f, 0.f};
        st[ct] = z;
      }
#pragma unroll
      for (int kd = 0; kd < 2; kd++)
#pragma unroll
        for (int ct = 0; ct < 2; ct++)
          st[ct] = __builtin_amdgcn_mfma_f32_16x16x32_bf16(
              ka[ct][kd], qf[tq][kd], st[ct], 0, 0, 0);
      unsigned pk[2][2];
#pragma unroll
      for (int ct = 0; ct < 2; ct++) {
        float p0 = fexp2(st[ct][0]);
        float p1 = fexp2(st[ct][1]);
        float p2 = fexp2(st[ct][2]);
        float p3 = fexp2(st[ct][3]);
        lres[tq] += (p0 + p1) + (p2 + p3);
        pk[ct][0] = pk2t(p0, p1);
        pk[ct][1] = pk2t(p2, p3);
      }
      // P B-frag via 4 bpermutes within the query column
      const int tt = quad >> 1;
      const int qs = (quad & 1) * 2;
      union {
        unsigned u[4];
        short8 s;
      } bu;
      bu.u[0] = (unsigned)__shfl((int)pk[tt][0], qs * 16 + ln);
      bu.u[1] = (unsigned)__shfl((int)pk[tt][1], qs * 16 + ln);
      bu.u[2] = (unsigned)__shfl((int)pk[tt][0], (qs + 1) * 16 + ln);
      bu.u[3] = (unsigned)__shfl((int)pk[tt][1], (qs + 1) * 16 + ln);
#pragma unroll
      for (int dt = 0; dt < 4; dt++)
        ot[tq][dt] = __builtin_amdgcn_mfma_f32_16x16x32_bf16(
            va[dt], bu.s, ot[tq][dt], 0, 0, 0);
    }
  };

  short8 kaA[2][2], kaB[2][2];
  STAGEV(0, 0);
  LOADK(kaA, 0);
  STAGEV(1, 1);
  LOADK(kaB, 1);
#pragma unroll 1
  for (int it = 0; it < 32; it += 2) {
    // step it (slot 0): retire {stage(it), kaA(it)} = oldest 8
    asm volatile("s_waitcnt vmcnt(8)" ::: "memory");
    __builtin_amdgcn_sched_barrier(0);
    READV(0);
    STEP(kaA);
    __builtin_amdgcn_sched_barrier(0);
    if (it < 30) {
      STAGEV(0, it + 2);
      LOADK(kaA, it + 2);
    }
    // step it+1 (slot 1)
    if (it < 30) {
      asm volatile("s_waitcnt vmcnt(8)" ::: "memory");
    } else {
      asm volatile("s_waitcnt vmcnt(0)" ::: "memory");
    }
    __builtin_amdgcn_sched_barrier(0);
    READV(1);
    STEP(kaB);
    __builtin_amdgcn_sched_barrier(0);
    if (it < 30) {
      STAGEV(1, it + 3);
      LOADK(kaB, it + 3);
    }
  }

  // per-tile: reduce l across quads; write partials (own staging bytes)
#pragma unroll
  for (int tq = 0; tq < 2; tq++) {
    float l = lres[tq];
    l += __shfl_xor(l, 16);
    l += __shfl_xor(l, 32);
    float* my = part + ((wave * 2 + tq) * 64 + lane) * 16;
#pragma unroll
    for (int dt = 0; dt < 4; dt++) *(f32x4*)&my[dt * 4] = ot[tq][dt];
    lsum[(wave * 2 + tq) * 64 + lane] = l;
  }
  __syncthreads();

  // 4-way combine: wave w handles tile (w&1), dh-half (w>>1).
  {
    const int tq = wave & 1;
    const float* p0 = part + ((0 + tq) * 64 + lane) * 16;
    const float* p1 = part + ((2 + tq) * 64 + lane) * 16;
    const float* p2 = part + ((4 + tq) * 64 + lane) * 16;
    const float* p3 = part + ((6 + tq) * 64 + lane) * 16;
    float lf = (lsum[(0 + tq) * 64 + lane] + lsum[(2 + tq) * 64 + lane]) +
               (lsum[(4 + tq) * 64 + lane] + lsum[(6 + tq) * 64 + lane]);
    float invl = 1.f / lf;
    int s = q0 + tq * 16 + ln;
    short* ap = attT + ((size_t)b * 4096 + s) * 256 + h * 64;
#pragma unroll
    for (int j = 0; j < 2; j++) {
      int dt = (wave >> 1) * 2 + j;
      f32x4 o0 = *(const f32x4*)&p0[dt * 4];
      f32x4 o1 = *(const f32x4*)&p1[dt * 4];
      f32x4 o2 = *(const f32x4*)&p2[dt * 4];
      f32x4 o3 = *(const f32x4*)&p3[dt * 4];
      uint2 u;
      u.x = pk2(((o0[0] + o1[0]) + (o2[0] + o3[0])) * invl,
                ((o0[1] + o1[1]) + (o2[1] + o3[1])) * invl);
      u.y = pk2(((o0[2] + o1[2]) + (o2[2] + o3[2])) * invl,
                ((o0[3] + o1[3]) + (o2[3] + o3[3])) * invl);
      *(uint2*)&ap[dt * 16 + quad * 4] = u;
    }
  }
}

// ---------------------------------------------------------------------------
// O-proj MFMA (r17 version — proven): 64s x 64o, per-kt staging, vectorized
// epilogue via fp32 LDS staging.
// ---------------------------------------------------------------------------
__global__ void __launch_bounds__(256) gemm_o_kernel(
    const short* __restrict__ owb, const short* __restrict__ attT,
    const float* __restrict__ obf, const void* __restrict__ xres,
    void* __restrict__ out, const int* __restrict__ flag) {
  __shared__ __align__(16) float ldsf[64 * 66];
  short* Bt = (short*)ldsf;  // attT tile [64 s][72]
  short* At = Bt + 64 * 72;  // o_w tile [64 o][72]
  const int t = threadIdx.x;
  const int wave = t >> 6, lane = t & 63;
  const int ln = lane & 15, quad = lane >> 4;
  const int s0 = blockIdx.x * 64, o0 = blockIdx.y * 64, b = blockIdx.z;
  const short* ag = attT + ((size_t)b * 4096 + s0) * 256;

  f32x4 acc[4];
#pragma unroll
  for (int mt = 0; mt < 4; mt++) {
    f32x4 z = {0.f, 0.f, 0.f, 0.f};
    acc[mt] = z;
  }

  for (int kt = 0; kt < 4; kt++) {
    __syncthreads();
    {
      int r = t >> 2, cq = t & 3;
#pragma unroll
      for (int j = 0; j < 2; j++)
        *(uint4*)&Bt[r * 72 + cq * 16 + j * 8] =
            *(const uint4*)&ag[(size_t)r * 256 + kt * 64 + cq * 16 + j * 8];
    }
    {
      int r = t >> 2, cq = t & 3;
#pragma unroll
      for (int j = 0; j < 2; j++)
        *(uint4*)&At[r * 72 + cq * 16 + j * 8] =
            *(const uint4*)&owb[(size_t)(o0 + r) * 256 + kt * 64 + cq * 16 +
                                j * 8];
    }
    __syncthreads();
#pragma unroll
    for (int kd = 0; kd < 2; kd++) {
      short8 a[4];
#pragma unroll
      for (int mt = 0; mt < 4; mt++)
        a[mt] = *(const short8*)&At[(mt * 16 + ln) * 72 + kd * 32 + quad * 8];
      short8 bb =
          *(const short8*)&Bt[(wave * 16 + ln) * 72 + kd * 32 + quad * 8];
#pragma unroll
      for (int mt = 0; mt < 4; mt++)
        acc[mt] = __builtin_amdgcn_mfma_f32_16x16x32_bf16(a[mt], bb, acc[mt],
                                                          0, 0, 0);
    }
  }

  __syncthreads();
#pragma unroll
  for (int mt = 0; mt < 4; mt++)
#pragma unroll
    for (int r = 0; r < 4; r++)
      ldsf[(mt * 16 + quad * 4 + r) * 66 + wave * 16 + ln] = acc[mt][r];
  __syncthreads();

  const int is32 = *flag;
#pragma unroll
  for (int j = 0; j < 4; j++) {
    int ol = j * 16 + (t >> 4);  // 0..63
    int sl = (t & 15) * 4;       // 0..60
    f32x4 v = *(const f32x4*)&ldsf[ol * 66 + sl];
    int o = o0 + ol;
    float bv = obf[o];
    size_t base = ((size_t)b * 256 + o) * 4096 + s0 + sl;
    if (is32) {
      const float4 rr = *(const float4*)&((const float*)xres)[base];
      float4 w;
      w.x = v[0] + bv + rr.x;
      w.y = v[1] + bv + rr.y;
      w.z = v[2] + bv + rr.z;
      w.w = v[3] + bv + rr.w;
      *(float4*)&((float*)out)[base] = w;
    } else {
      const uint2 rr = *(const uint2*)&((const bf16*)xres)[base];
      uint2 w;
      w.x = pk2(v[0] + bv + blo(rr.x), v[1] + bv + bhi(rr.x));
      w.y = pk2(v[2] + bv + blo(rr.y), v[3] + bv + bhi(rr.y));
      *(uint2*)&((bf16*)out)[base] = w;
    }
  }
}

// ---------------------------------------------------------------------------
extern "C" void kernel_launch(void* const* d_in, const int* in_sizes, int n_in,
                              void* d_out, int out_size, void* d_ws,
                              size_t ws_size, hipStream_t stream) {
  float* ws = (float*)d_ws;
  int* flag = (int*)ws;                  // @0
  float* scale = ws + 256;               // 512
  float* shift = ws + 768;               // 512
  float* bias2 = ws + 1280;              // 1536
  float* obf = ws + 2816;                // 256
  short* owb = (short*)(ws + 3072);      // 65536 shorts
  short* W2 = (short*)(ws + 35840);      // 393216 shorts
  short* xT = (short*)(ws + 232448);     // [b][4096][256] bf16
  short* qT = (short*)(ws + 1281024);    // [bh][4096][64] bf16 (row-major)
  short* kF = (short*)(ws + 2329600);    // [bh] frag-major K, 262144 ea
  short* vF = (short*)(ws + 3378176);    // [bh] frag-major V, 262144 ea
  short* attT = (short*)(ws + 4426752);  // [b][4096][256] bf16

  detect_kernel<<<1, 256, 0, stream>>>(d_in[0], flag);
  pre1_kernel<<<576, 256, 0, stream>>>(d_in[0], d_in[1], d_in[2], flag, scale,
                                       shift, xT);
  pre2_kernel<<<dim3(256, 2), 256, 0, stream>>>(d_in[3], d_in[4], d_in[5],
                                                scale, shift, flag, W2, bias2,
                                                owb, obf);
  gemm_qkv_kernel<<<dim3(32, 12, 2), 256, 0, stream>>>(xT, W2, bias2, qT, kF,
                                                       vF);
  flash_kernel<<<1024, 256, 0, stream>>>(qT, kF, vF, attT);
  gemm_o_kernel<<<dim3(64, 4, 2), 256, 0, stream>>>(owb, attT, obf, d_in[0],
                                                    d_out, flag);
}

// Round 15
// 166.713 us; speedup vs baseline: 1.4498x; 1.4498x over previous
//
#include <hip/hip_runtime.h>
#include <hip/hip_bf16.h>

typedef __hip_bfloat16 bf16;
typedef short short8 __attribute__((ext_vector_type(8)));  // 8 bf16 (4 VGPRs)
typedef float f32x4 __attribute__((ext_vector_type(4)));

__device__ __forceinline__ float b2f(bf16 v) { return __bfloat162float(v); }

// RNE fp32 -> bf16
__device__ __forceinline__ unsigned short f2bf(float x) {
  unsigned u = __builtin_bit_cast(unsigned, x);
  unsigned r = u + 0x7fffu + ((u >> 16) & 1u);
  return (unsigned short)(r >> 16);
}
__device__ __forceinline__ unsigned pk2(float a, float b) {
  return (unsigned)f2bf(a) | ((unsigned)f2bf(b) << 16);
}
// truncating pack via single v_perm_b32: dst = {a.hi16, b.hi16}
__device__ __forceinline__ unsigned pk2t(float a, float b) {
  return __builtin_amdgcn_perm(__builtin_bit_cast(unsigned, b),
                               __builtin_bit_cast(unsigned, a), 0x07060302u);
}
__device__ __forceinline__ float rd(const void* p, size_t i, int is32) {
  return is32 ? ((const float*)p)[i] : b2f(((const bf16*)p)[i]);
}
__device__ __forceinline__ float blo(unsigned w) {
  return __builtin_bit_cast(float, w << 16);
}
__device__ __forceinline__ float bhi(unsigned w) {
  return __builtin_bit_cast(float, w & 0xffff0000u);
}
// raw v_exp_f32 (scores bounded; no OCML special-casing)
__device__ __forceinline__ float fexp2(float x) {
  return __builtin_amdgcn_exp2f(x);
}
// async global->LDS, 16B per lane; LDS dest wave-uniform base + lane*16
__device__ __forceinline__ void gld_lds16(const void* g, void* l) {
  __builtin_amdgcn_global_load_lds(
      (const __attribute__((address_space(1))) unsigned int*)g,
      (__attribute__((address_space(3))) unsigned int*)l, 16, 0, 0);
}

#define CQ 0.09016844005556022f  // (1/16) * log2(e), folded into q weights

// ---------------------------------------------------------------------------
// dtype detect: flag=1 fp32, flag=0 bf16 (see round-1 notes)
// ---------------------------------------------------------------------------
__global__ void __launch_bounds__(256) detect_kernel(const void* __restrict__ x,
                                                     int* __restrict__ flag) {
  __shared__ int cnt[256];
  const bf16* xb = (const bf16*)x;
  int c = 0;
  for (int i = threadIdx.x; i < 4096; i += 256) {
    float v = fabsf(b2f(xb[2 * i]));
    if (v >= 0.0009765625f && v <= 1024.0f) c++;
  }
  cnt[threadIdx.x] = c;
  __syncthreads();
  for (int off = 128; off > 0; off >>= 1) {
    if (threadIdx.x < off) cnt[threadIdx.x] += cnt[threadIdx.x + off];
    __syncthreads();
  }
  if (threadIdx.x == 0) *flag = (cnt[0] < 2048) ? 1 : 0;
}

// ---------------------------------------------------------------------------
// pre1: fused xt (blocks 0..511, vectorized loads) + gn_stats (blocks 512..575)
// ---------------------------------------------------------------------------
__global__ void __launch_bounds__(256) pre1_kernel(
    const void* __restrict__ x, const void* __restrict__ gn_w,
    const void* __restrict__ gn_b, const int* __restrict__ flag,
    float* __restrict__ scale, float* __restrict__ shift,
    short* __restrict__ xT) {
  __shared__ __align__(16) float F[64][72];
  const int t = threadIdx.x;
  const int is32 = *flag;
  if (blockIdx.x < 512) {
    const int bx = blockIdx.x;
    const int b = bx >> 8, rest = bx & 255;
    const int s0 = (rest >> 2) * 64, c0 = (rest & 3) * 64;
    if (is32) {
      const float* xp = (const float*)x;
#pragma unroll
      for (int k = 0; k < 4; k++) {
        int idx = k * 256 + t, cl = idx >> 4, c4 = idx & 15;
        float4 v = *(const float4*)&xp[(size_t)(b * 256 + c0 + cl) * 4096 + s0 +
                                       c4 * 4];
        *(float4*)&F[cl][c4 * 4] = v;
      }
    } else {
      const bf16* xp = (const bf16*)x;
#pragma unroll
      for (int k = 0; k < 2; k++) {
        int idx = k * 256 + t, cl = idx >> 3, c8 = idx & 7;
        uint4 u = *(const uint4*)&xp[(size_t)(b * 256 + c0 + cl) * 4096 + s0 +
                                     c8 * 8];
        float4 f0, f1;
        f0.x = blo(u.x); f0.y = bhi(u.x); f0.z = blo(u.y); f0.w = bhi(u.y);
        f1.x = blo(u.z); f1.y = bhi(u.z); f1.z = blo(u.w); f1.w = bhi(u.w);
        *(float4*)&F[cl][c8 * 8] = f0;
        *(float4*)&F[cl][c8 * 8 + 4] = f1;
      }
    }
    __syncthreads();
#pragma unroll
    for (int k = 0; k < 8; k++) {
      int idx = k * 256 + t;
      int sl = idx >> 5, c2 = (idx & 31) * 2;
      unsigned u = pk2(F[c2][sl], F[c2 + 1][sl]);
      *(unsigned*)&xT[((size_t)b * 4096 + s0 + sl) * 256 + c0 + c2] = u;
    }
  } else {
    const int idx0 = blockIdx.x - 512;
    const int b = idx0 >> 5, g = idx0 & 31;
    const size_t base = (size_t)(b * 256 + g * 8) * 4096;
    float s = 0.f, ss = 0.f;
    if (is32) {
      const float4* p = (const float4*)((const float*)x + base);
      for (int i = t; i < 8192; i += 256) {
        float4 v = p[i];
        s += (v.x + v.y) + (v.z + v.w);
        ss += v.x * v.x + v.y * v.y + v.z * v.z + v.w * v.w;
      }
    } else {
      const uint4* p = (const uint4*)((const bf16*)x + base);
      for (int i = t; i < 4096; i += 256) {
        uint4 u = p[i];
#pragma unroll
        for (int k = 0; k < 4; k++) {
          unsigned w = (&u.x)[k];
          float lo = blo(w), hi = bhi(w);
          s += lo + hi;
          ss += lo * lo + hi * hi;
        }
      }
    }
    float* rs = &F[0][0];
    float* rq = rs + 256;
    rs[t] = s;
    rq[t] = ss;
    __syncthreads();
    for (int off = 128; off > 0; off >>= 1) {
      if (t < off) {
        rs[t] += rs[t + off];
        rq[t] += rq[t + off];
      }
      __syncthreads();
    }
    if (t < 8) {
      const float inv_n = 1.f / 32768.f;
      float mean = rs[0] * inv_n;
      float var = rq[0] * inv_n - mean * mean;
      float rstd = rsqrtf(var + 1e-5f);
      int c = g * 8 + t;
      float sc = rd(gn_w, c, is32) * rstd;
      scale[b * 256 + c] = sc;
      shift[b * 256 + c] = rd(gn_b, c, is32) - mean * sc;
    }
  }
}

// ---------------------------------------------------------------------------
// pre2: fused prep_w (bx<192) + conv_o (bx>=192, by==0).
// ---------------------------------------------------------------------------
__global__ void __launch_bounds__(256) pre2_kernel(
    const void* __restrict__ qkv_w, const void* __restrict__ o_w,
    const void* __restrict__ o_b, const float* __restrict__ scale,
    const float* __restrict__ shift, const int* __restrict__ flag,
    short* __restrict__ W2, float* __restrict__ bias2, short* __restrict__ owb,
    float* __restrict__ obf) {
  const int is32 = *flag;
  if (blockIdx.x < 192) {
    const int b = blockIdx.y;
    const int o = blockIdx.x * 4 + (threadIdx.x >> 6);
    const int lane = threadIdx.x & 63;
    const float f = (o % 192 < 64) ? CQ : 1.0f;
    float w[4], acc = 0.f;
#pragma unroll
    for (int k = 0; k < 4; k++) {
      int c = lane * 4 + k;
      w[k] = rd(qkv_w, (size_t)o * 256 + c, is32);
      acc += w[k] * shift[b * 256 + c];
      w[k] = w[k] * scale[b * 256 + c] * f;
    }
#pragma unroll
    for (int m = 1; m < 64; m <<= 1) acc += __shfl_xor(acc, m);
    if (lane == 0) bias2[b * 768 + o] = acc * f;
    uint2 u;
    u.x = pk2(w[0], w[1]);
    u.y = pk2(w[2], w[3]);
    *(uint2*)&W2[((size_t)b * 768 + o) * 256 + lane * 4] = u;
  } else if (blockIdx.y == 0) {
    int bx = blockIdx.x - 192;  // 0..63
    int i = (bx * 256 + threadIdx.x) * 4;
    uint2 u;
    u.x = pk2(rd(o_w, i, is32), rd(o_w, i + 1, is32));
    u.y = pk2(rd(o_w, i + 2, is32), rd(o_w, i + 3, is32));
    *(uint2*)&owb[i] = u;
    if (bx == 0) obf[threadIdx.x] = rd(o_b, threadIdx.x, is32);
  }
}

// ---------------------------------------------------------------------------
// QKV MFMA GEMM (r15/r17 version — proven): D[s][o] = xT·W2^T (+bias2).
// Block 128s x 64o, per-kt staging. seg 0 (q): row-major qT. seg 1 (k):
// fragment-major Kf. seg 2 (v): transpose + fragment-major Vf.
// ---------------------------------------------------------------------------
__global__ void __launch_bounds__(256) gemm_qkv_kernel(
    const short* __restrict__ xT, const short* __restrict__ W2,
    const float* __restrict__ bias2, short* __restrict__ qT,
    short* __restrict__ kF, short* __restrict__ vF) {
  __shared__ __align__(16) short lds[128 * 72 + 64 * 72];
  short* At = lds;             // xT tile [128 s][72]
  short* Bt = lds + 128 * 72;  // W2 tile [64 o][72]
  const int t = threadIdx.x;
  const int wave = t >> 6, lane = t & 63;
  const int ln = lane & 15, quad = lane >> 4;
  const int s0 = blockIdx.x * 128, by = blockIdx.y, b = blockIdx.z;
  const int o0 = by * 64;
  const short* xg = xT + ((size_t)b * 4096 + s0) * 256;
  const short* wg = W2 + ((size_t)b * 768 + o0) * 256;

  f32x4 acc[2][4];
#pragma unroll
  for (int mt = 0; mt < 2; mt++)
#pragma unroll
    for (int nt = 0; nt < 4; nt++) {
      f32x4 z = {0.f, 0.f, 0.f, 0.f};
      acc[mt][nt] = z;
    }

  for (int kt = 0; kt < 4; kt++) {
    __syncthreads();
    {
      int r = t >> 1, ch = t & 1;
#pragma unroll
      for (int j = 0; j < 4; j++)
        *(uint4*)&At[r * 72 + ch * 32 + j * 8] =
            *(const uint4*)&xg[(size_t)r * 256 + kt * 64 + ch * 32 + j * 8];
    }
    {
      int r = t >> 2, cq = t & 3;
#pragma unroll
      for (int j = 0; j < 2; j++)
        *(uint4*)&Bt[r * 72 + cq * 16 + j * 8] =
            *(const uint4*)&wg[(size_t)r * 256 + kt * 64 + cq * 16 + j * 8];
    }
    __syncthreads();
#pragma unroll
    for (int kd = 0; kd < 2; kd++) {
      short8 a[2], bb[4];
#pragma unroll
      for (int mt = 0; mt < 2; mt++)
        a[mt] = *(const short8*)&At[(wave * 32 + mt * 16 + ln) * 72 + kd * 32 +
                                    quad * 8];
#pragma unroll
      for (int nt = 0; nt < 4; nt++)
        bb[nt] = *(const short8*)&Bt[(nt * 16 + ln) * 72 + kd * 32 + quad * 8];
#pragma unroll
      for (int mt = 0; mt < 2; mt++)
#pragma unroll
        for (int nt = 0; nt < 4; nt++)
          acc[mt][nt] = __builtin_amdgcn_mfma_f32_16x16x32_bf16(
              a[mt], bb[nt], acc[mt][nt], 0, 0, 0);
    }
  }

  const int h = by / 3, seg = by % 3;
  const size_t bh = (size_t)b * 4 + h;
  __syncthreads();
  if (seg != 2) {
    short* T = At;  // [128 s][72] = [key_local][dh]
#pragma unroll
    for (int mt = 0; mt < 2; mt++)
#pragma unroll
      for (int nt = 0; nt < 4; nt++)
#pragma unroll
        for (int r = 0; r < 4; r++)
          T[(wave * 32 + mt * 16 + quad * 4 + r) * 72 + nt * 16 + ln] =
              (short)f2bf(acc[mt][nt][r] + bias2[b * 768 + o0 + nt * 16 + ln]);
    __syncthreads();
    if (seg == 0) {  // q: row-major
      short* dst = qT + (bh * 4096 + s0) * 64;
      int r = t >> 1, ch = t & 1;
#pragma unroll
      for (int j = 0; j < 2; j++)
        *(uint4*)&dst[r * 64 + ch * 32 + j * 8] =
            *(const uint4*)&T[r * 72 + ch * 32 + j * 8];
    } else {  // k: fragment-major
      short* dstf = kF + bh * 262144;
#pragma unroll
      for (int c = 0; c < 4; c++) {
        int cid = wave * 4 + c;
        int tile = cid >> 1, kd = cid & 1;
        short8 v =
            *(const short8*)&T[(tile * 16 + ln) * 72 + kd * 32 + quad * 8];
        *(short8*)&dstf[(size_t)((s0 / 16 + tile) * 2 + kd) * 512 + lane * 8] =
            v;
      }
    }
  } else {
    short* T2 = At;  // [64 dh][132 key_local]
#pragma unroll
    for (int mt = 0; mt < 2; mt++)
#pragma unroll
      for (int nt = 0; nt < 4; nt++) {
        float bv = bias2[b * 768 + o0 + nt * 16 + ln];
        uint2 u;
        u.x = pk2(acc[mt][nt][0] + bv, acc[mt][nt][1] + bv);
        u.y = pk2(acc[mt][nt][2] + bv, acc[mt][nt][3] + bv);
        *(uint2*)&T2[(nt * 16 + ln) * 132 + wave * 32 + mt * 16 + quad * 4] = u;
      }
    __syncthreads();
    short* dstf = vF + bh * 262144;
#pragma unroll
    for (int c = 0; c < 4; c++) {
      int cid = wave * 4 + c;
      int ktl = cid >> 3, rem = cid & 7, dt = rem >> 1, kc = rem & 1;
      short8 v = *(const short8*)&T2[(dt * 16 + ln) * 132 + ktl * 64 + kc * 32 +
                                     quad * 8];
      *(short8*)&dstf[(size_t)(((s0 / 64 + ktl) * 4 + dt) * 2 + kc) * 512 +
                      lane * 8] = v;
    }
  }
}

// ---------------------------------------------------------------------------
// Flash MFMA v19: LDS-SHARED K/V (the r10 pre-committed pivot). Evidence:
// v15 is L2-BW-bound (1 GB issue / 64.7 us = 16.6 TB/s ~ 50% of ceiling);
// all three latency-depth attempts (v16 reg-widen, v17 restructure, v18
// LDS-DMA+pinned sched) spilled ~100-270 MB scratch at the stubborn
// 64-VGPR tier. v19 cuts TRAFFIC instead: grid 512 (8 bh x 64 q-groups),
// block = 64 q, wave = 16 q; all 4 waves walk ALL 4096 keys from
// double-buffered LDS tiles (64 keys: 8 KB K + 8 KB V, contiguous in the
// frag-major layouts), staged cooperatively via global_load_lds (4 per
// wave per tile). Issue volume: 512 x 1 MB = 512 MB (2x cut), each staged
// byte feeds 4 waves. No split-K -> no combine; each wave owns complete
// softmax rows and writes directly. Registers DROP (qf[2]+ot[4]+ka+va
// ~60 live); launch_bounds(256,2) gives 256-VGPR headroom -> no spill.
// Sync: plain vmcnt(0)+barrier per 64-key tile; DMA for tile kt+1 issued
// before compute on kt (~1200 cyc cover). LDS 32 KB.
// ---------------------------------------------------------------------------
__global__ void __launch_bounds__(256, 2) flash_kernel(
    const short* __restrict__ qT, const short* __restrict__ kF,
    const short* __restrict__ vF, short* __restrict__ attT) {
  __shared__ __align__(16) short KV[2][8192];  // buf: K[0,4096) V[4096,8192)
  const int t = threadIdx.x;
  const int wave = t >> 6, lane = t & 63;
  const int ln = lane & 15, quad = lane >> 4;
  const int L = blockIdx.x;
  const int bh = L & 7;  // XCD-pinned head stream
  const int b = bh >> 2, h = bh & 3;
  const int q0 = (L >> 3) * 64;

  const short* qg = qT + ((size_t)bh * 4096 + q0 + wave * 16) * 64;
  const short* kf = kF + (size_t)bh * 262144;
  const short* vf = vF + (size_t)bh * 262144;

  short8 qf[2];
#pragma unroll
  for (int kd = 0; kd < 2; kd++)
    qf[kd] = *(const short8*)&qg[ln * 64 + kd * 32 + quad * 8];

  f32x4 ot[4];
#pragma unroll
  for (int dt = 0; dt < 4; dt++) {
    f32x4 z = {0.f, 0.f, 0.f, 0.f};
    ot[dt] = z;
  }
  float lres = 0.f;

  // stage 64-key tile kt into buffer bu (16 KB, 4 DMA per wave)
  auto STAGE = [&](int bu, int kt) {
    const short* ks = kf + (size_t)kt * 4096;
    const short* vs = vf + (size_t)kt * 4096;
#pragma unroll
    for (int j = 0; j < 2; j++) {
      gld_lds16(&ks[wave * 1024 + j * 512 + lane * 8],
                &KV[bu][wave * 1024 + j * 512]);
      gld_lds16(&vs[wave * 1024 + j * 512 + lane * 8],
                &KV[bu][4096 + wave * 1024 + j * 512]);
    }
  };

  // 16 q x 32 keys (subtile s32 of the 64-key buffer bu)
  auto STEP = [&](int bu, int s32) {
    short8 ka[2][2], va[4];
#pragma unroll
    for (int ct = 0; ct < 2; ct++)
#pragma unroll
      for (int kd = 0; kd < 2; kd++)
        ka[ct][kd] = *(const short8*)&KV[bu][((s32 * 2 + ct) * 2 + kd) * 512 +
                                            lane * 8];
#pragma unroll
    for (int dt = 0; dt < 4; dt++)
      va[dt] =
          *(const short8*)&KV[bu][4096 + (dt * 2 + s32) * 512 + lane * 8];

    f32x4 st[2];
#pragma unroll
    for (int ct = 0; ct < 2; ct++) {
      f32x4 z = {0.f, 0.f, 0.f, 0.f};
      st[ct] = z;
    }
#pragma unroll
    for (int kd = 0; kd < 2; kd++)
#pragma unroll
      for (int ct = 0; ct < 2; ct++)
        st[ct] = __builtin_amdgcn_mfma_f32_16x16x32_bf16(ka[ct][kd], qf[kd],
                                                         st[ct], 0, 0, 0);
    unsigned pk[2][2];
#pragma unroll
    for (int ct = 0; ct < 2; ct++) {
      float p0 = fexp2(st[ct][0]);
      float p1 = fexp2(st[ct][1]);
      float p2 = fexp2(st[ct][2]);
      float p3 = fexp2(st[ct][3]);
      lres += (p0 + p1) + (p2 + p3);
      pk[ct][0] = pk2t(p0, p1);
      pk[ct][1] = pk2t(p2, p3);
    }
    // P B-frag via 4 bpermutes within the query column (v15 mapping)
    const int tt = quad >> 1;
    const int qs = (quad & 1) * 2;
    union {
      unsigned u[4];
      short8 s;
    } pu;
    pu.u[0] = (unsigned)__shfl((int)pk[tt][0], qs * 16 + ln);
    pu.u[1] = (unsigned)__shfl((int)pk[tt][1], qs * 16 + ln);
    pu.u[2] = (unsigned)__shfl((int)pk[tt][0], (qs + 1) * 16 + ln);
    pu.u[3] = (unsigned)__shfl((int)pk[tt][1], (qs + 1) * 16 + ln);
#pragma unroll
    for (int dt = 0; dt < 4; dt++)
      ot[dt] = __builtin_amdgcn_mfma_f32_16x16x32_bf16(va[dt], pu.s, ot[dt],
                                                       0, 0, 0);
  };

  STAGE(0, 0);
  asm volatile("s_waitcnt vmcnt(0)" ::: "memory");
  __syncthreads();
#pragma unroll 1
  for (int kt = 0; kt < 64; kt++) {
    const int cur = kt & 1;
    if (kt < 63) STAGE(cur ^ 1, kt + 1);
    STEP(cur, 0);
    STEP(cur, 1);
    asm volatile("s_waitcnt vmcnt(0)" ::: "memory");
    __syncthreads();
  }

  // epilogue: complete rows per wave -> normalize and write directly
  lres += __shfl_xor(lres, 16);
  lres += __shfl_xor(lres, 32);
  float invl = 1.f / lres;
  int s = q0 + wave * 16 + ln;
  short* ap = attT + ((size_t)b * 4096 + s) * 256 + h * 64;
#pragma unroll
  for (int dt = 0; dt < 4; dt++) {
    uint2 u;
    u.x = pk2(ot[dt][0] * invl, ot[dt][1] * invl);
    u.y = pk2(ot[dt][2] * invl, ot[dt][3] * invl);
    *(uint2*)&ap[dt * 16 + quad * 4] = u;
  }
}

// ---------------------------------------------------------------------------
// O-proj MFMA (r17 version — proven): 64s x 64o, per-kt staging, vectorized
// epilogue via fp32 LDS staging.
// ---------------------------------------------------------------------------
__global__ void __launch_bounds__(256) gemm_o_kernel(
    const short* __restrict__ owb, const short* __restrict__ attT,
    const float* __restrict__ obf, const void* __restrict__ xres,
    void* __restrict__ out, const int* __restrict__ flag) {
  __shared__ __align__(16) float ldsf[64 * 66];
  short* Bt = (short*)ldsf;  // attT tile [64 s][72]
  short* At = Bt + 64 * 72;  // o_w tile [64 o][72]
  const int t = threadIdx.x;
  const int wave = t >> 6, lane = t & 63;
  const int ln = lane & 15, quad = lane >> 4;
  const int s0 = blockIdx.x * 64, o0 = blockIdx.y * 64, b = blockIdx.z;
  const short* ag = attT + ((size_t)b * 4096 + s0) * 256;

  f32x4 acc[4];
#pragma unroll
  for (int mt = 0; mt < 4; mt++) {
    f32x4 z = {0.f, 0.f, 0.f, 0.f};
    acc[mt] = z;
  }

  for (int kt = 0; kt < 4; kt++) {
    __syncthreads();
    {
      int r = t >> 2, cq = t & 3;
#pragma unroll
      for (int j = 0; j < 2; j++)
        *(uint4*)&Bt[r * 72 + cq * 16 + j * 8] =
            *(const uint4*)&ag[(size_t)r * 256 + kt * 64 + cq * 16 + j * 8];
    }
    {
      int r = t >> 2, cq = t & 3;
#pragma unroll
      for (int j = 0; j < 2; j++)
        *(uint4*)&At[r * 72 + cq * 16 + j * 8] =
            *(const uint4*)&owb[(size_t)(o0 + r) * 256 + kt * 64 + cq * 16 +
                                j * 8];
    }
    __syncthreads();
#pragma unroll
    for (int kd = 0; kd < 2; kd++) {
      short8 a[4];
#pragma unroll
      for (int mt = 0; mt < 4; mt++)
        a[mt] = *(const short8*)&At[(mt * 16 + ln) * 72 + kd * 32 + quad * 8];
      short8 bb =
          *(const short8*)&Bt[(wave * 16 + ln) * 72 + kd * 32 + quad * 8];
#pragma unroll
      for (int mt = 0; mt < 4; mt++)
        acc[mt] = __builtin_amdgcn_mfma_f32_16x16x32_bf16(a[mt], bb, acc[mt],
                                                          0, 0, 0);
    }
  }

  __syncthreads();
#pragma unroll
  for (int mt = 0; mt < 4; mt++)
#pragma unroll
    for (int r = 0; r < 4; r++)
      ldsf[(mt * 16 + quad * 4 + r) * 66 + wave * 16 + ln] = acc[mt][r];
  __syncthreads();

  const int is32 = *flag;
#pragma unroll
  for (int j = 0; j < 4; j++) {
    int ol = j * 16 + (t >> 4);  // 0..63
    int sl = (t & 15) * 4;       // 0..60
    f32x4 v = *(const f32x4*)&ldsf[ol * 66 + sl];
    int o = o0 + ol;
    float bv = obf[o];
    size_t base = ((size_t)b * 256 + o) * 4096 + s0 + sl;
    if (is32) {
      const float4 rr = *(const float4*)&((const float*)xres)[base];
      float4 w;
      w.x = v[0] + bv + rr.x;
      w.y = v[1] + bv + rr.y;
      w.z = v[2] + bv + rr.z;
      w.w = v[3] + bv + rr.w;
      *(float4*)&((float*)out)[base] = w;
    } else {
      const uint2 rr = *(const uint2*)&((const bf16*)xres)[base];
      uint2 w;
      w.x = pk2(v[0] + bv + blo(rr.x), v[1] + bv + bhi(rr.x));
      w.y = pk2(v[2] + bv + blo(rr.y), v[3] + bv + bhi(rr.y));
      *(uint2*)&((bf16*)out)[base] = w;
    }
  }
}

// ---------------------------------------------------------------------------
extern "C" void kernel_launch(void* const* d_in, const int* in_sizes, int n_in,
                              void* d_out, int out_size, void* d_ws,
                              size_t ws_size, hipStream_t stream) {
  float* ws = (float*)d_ws;
  int* flag = (int*)ws;                  // @0
  float* scale = ws + 256;               // 512
  float* shift = ws + 768;               // 512
  float* bias2 = ws + 1280;              // 1536
  float* obf = ws + 2816;                // 256
  short* owb = (short*)(ws + 3072);      // 65536 shorts
  short* W2 = (short*)(ws + 35840);      // 393216 shorts
  short* xT = (short*)(ws + 232448);     // [b][4096][256] bf16
  short* qT = (short*)(ws + 1281024);    // [bh][4096][64] bf16 (row-major)
  short* kF = (short*)(ws + 2329600);    // [bh] frag-major K, 262144 ea
  short* vF = (short*)(ws + 3378176);    // [bh] frag-major V, 262144 ea
  short* attT = (short*)(ws + 4426752);  // [b][4096][256] bf16

  detect_kernel<<<1, 256, 0, stream>>>(d_in[0], flag);
  pre1_kernel<<<576, 256, 0, stream>>>(d_in[0], d_in[1], d_in[2], flag, scale,
                                       shift, xT);
  pre2_kernel<<<dim3(256, 2), 256, 0, stream>>>(d_in[3], d_in[4], d_in[5],
                                                scale, shift, flag, W2, bias2,
                                                owb, obf);
  gemm_qkv_kernel<<<dim3(32, 12, 2), 256, 0, stream>>>(xT, W2, bias2, qT, kF,
                                                       vF);
  flash_kernel<<<512, 256, 0, stream>>>(qT, kF, vF, attT);
  gemm_o_kernel<<<dim3(64, 4, 2), 256, 0, stream>>>(owb, attT, obf, d_in[0],
                                                    d_out, flag);
}

// Round 19
// 161.702 us; speedup vs baseline: 1.4947x; 1.0310x over previous
//
#include <hip/hip_runtime.h>
#include <hip/hip_bf16.h>

typedef __hip_bfloat16 bf16;
typedef short short8 __attribute__((ext_vector_type(8)));  // 8 bf16 (4 VGPRs)
typedef float f32x4 __attribute__((ext_vector_type(4)));

__device__ __forceinline__ float b2f(bf16 v) { return __bfloat162float(v); }

// RNE fp32 -> bf16
__device__ __forceinline__ unsigned short f2bf(float x) {
  unsigned u = __builtin_bit_cast(unsigned, x);
  unsigned r = u + 0x7fffu + ((u >> 16) & 1u);
  return (unsigned short)(r >> 16);
}
__device__ __forceinline__ unsigned pk2(float a, float b) {
  return (unsigned)f2bf(a) | ((unsigned)f2bf(b) << 16);
}
// truncating pack via single v_perm_b32: dst = {a.hi16, b.hi16}
__device__ __forceinline__ unsigned pk2t(float a, float b) {
  return __builtin_amdgcn_perm(__builtin_bit_cast(unsigned, b),
                               __builtin_bit_cast(unsigned, a), 0x07060302u);
}
__device__ __forceinline__ float rd(const void* p, size_t i, int is32) {
  return is32 ? ((const float*)p)[i] : b2f(((const bf16*)p)[i]);
}
__device__ __forceinline__ float blo(unsigned w) {
  return __builtin_bit_cast(float, w << 16);
}
__device__ __forceinline__ float bhi(unsigned w) {
  return __builtin_bit_cast(float, w & 0xffff0000u);
}
// raw v_exp_f32 (scores bounded; no OCML special-casing)
__device__ __forceinline__ float fexp2(float x) {
  return __builtin_amdgcn_exp2f(x);
}

#define CQ 0.09016844005556022f  // (1/16) * log2(e), folded into q weights

// ---------------------------------------------------------------------------
// dtype detect: flag=1 fp32, flag=0 bf16 (see round-1 notes)
// ---------------------------------------------------------------------------
__global__ void __launch_bounds__(256) detect_kernel(const void* __restrict__ x,
                                                     int* __restrict__ flag) {
  __shared__ int cnt[256];
  const bf16* xb = (const bf16*)x;
  int c = 0;
  for (int i = threadIdx.x; i < 4096; i += 256) {
    float v = fabsf(b2f(xb[2 * i]));
    if (v >= 0.0009765625f && v <= 1024.0f) c++;
  }
  cnt[threadIdx.x] = c;
  __syncthreads();
  for (int off = 128; off > 0; off >>= 1) {
    if (threadIdx.x < off) cnt[threadIdx.x] += cnt[threadIdx.x + off];
    __syncthreads();
  }
  if (threadIdx.x == 0) *flag = (cnt[0] < 2048) ? 1 : 0;
}

// ---------------------------------------------------------------------------
// pre1: fused xt (blocks 0..511, vectorized loads) + gn_stats (blocks 512..575)
// ---------------------------------------------------------------------------
__global__ void __launch_bounds__(256) pre1_kernel(
    const void* __restrict__ x, const void* __restrict__ gn_w,
    const void* __restrict__ gn_b, const int* __restrict__ flag,
    float* __restrict__ scale, float* __restrict__ shift,
    short* __restrict__ xT) {
  __shared__ __align__(16) float F[64][72];
  const int t = threadIdx.x;
  const int is32 = *flag;
  if (blockIdx.x < 512) {
    const int bx = blockIdx.x;
    const int b = bx >> 8, rest = bx & 255;
    const int s0 = (rest >> 2) * 64, c0 = (rest & 3) * 64;
    if (is32) {
      const float* xp = (const float*)x;
#pragma unroll
      for (int k = 0; k < 4; k++) {
        int idx = k * 256 + t, cl = idx >> 4, c4 = idx & 15;
        float4 v = *(const float4*)&xp[(size_t)(b * 256 + c0 + cl) * 4096 + s0 +
                                       c4 * 4];
        *(float4*)&F[cl][c4 * 4] = v;
      }
    } else {
      const bf16* xp = (const bf16*)x;
#pragma unroll
      for (int k = 0; k < 2; k++) {
        int idx = k * 256 + t, cl = idx >> 3, c8 = idx & 7;
        uint4 u = *(const uint4*)&xp[(size_t)(b * 256 + c0 + cl) * 4096 + s0 +
                                     c8 * 8];
        float4 f0, f1;
        f0.x = blo(u.x); f0.y = bhi(u.x); f0.z = blo(u.y); f0.w = bhi(u.y);
        f1.x = blo(u.z); f1.y = bhi(u.z); f1.z = blo(u.w); f1.w = bhi(u.w);
        *(float4*)&F[cl][c8 * 8] = f0;
        *(float4*)&F[cl][c8 * 8 + 4] = f1;
      }
    }
    __syncthreads();
#pragma unroll
    for (int k = 0; k < 8; k++) {
      int idx = k * 256 + t;
      int sl = idx >> 5, c2 = (idx & 31) * 2;
      unsigned u = pk2(F[c2][sl], F[c2 + 1][sl]);
      *(unsigned*)&xT[((size_t)b * 4096 + s0 + sl) * 256 + c0 + c2] = u;
    }
  } else {
    const int idx0 = blockIdx.x - 512;
    const int b = idx0 >> 5, g = idx0 & 31;
    const size_t base = (size_t)(b * 256 + g * 8) * 4096;
    float s = 0.f, ss = 0.f;
    if (is32) {
      const float4* p = (const float4*)((const float*)x + base);
      for (int i = t; i < 8192; i += 256) {
        float4 v = p[i];
        s += (v.x + v.y) + (v.z + v.w);
        ss += v.x * v.x + v.y * v.y + v.z * v.z + v.w * v.w;
      }
    } else {
      const uint4* p = (const uint4*)((const bf16*)x + base);
      for (int i = t; i < 4096; i += 256) {
        uint4 u = p[i];
#pragma unroll
        for (int k = 0; k < 4; k++) {
          unsigned w = (&u.x)[k];
          float lo = blo(w), hi = bhi(w);
          s += lo + hi;
          ss += lo * lo + hi * hi;
        }
      }
    }
    float* rs = &F[0][0];
    float* rq = rs + 256;
    rs[t] = s;
    rq[t] = ss;
    __syncthreads();
    for (int off = 128; off > 0; off >>= 1) {
      if (t < off) {
        rs[t] += rs[t + off];
        rq[t] += rq[t + off];
      }
      __syncthreads();
    }
    if (t < 8) {
      const float inv_n = 1.f / 32768.f;
      float mean = rs[0] * inv_n;
      float var = rq[0] * inv_n - mean * mean;
      float rstd = rsqrtf(var + 1e-5f);
      int c = g * 8 + t;
      float sc = rd(gn_w, c, is32) * rstd;
      scale[b * 256 + c] = sc;
      shift[b * 256 + c] = rd(gn_b, c, is32) - mean * sc;
    }
  }
}

// ---------------------------------------------------------------------------
// pre2: fused prep_w (bx<192) + conv_o (bx>=192, by==0).
// ---------------------------------------------------------------------------
__global__ void __launch_bounds__(256) pre2_kernel(
    const void* __restrict__ qkv_w, const void* __restrict__ o_w,
    const void* __restrict__ o_b, const float* __restrict__ scale,
    const float* __restrict__ shift, const int* __restrict__ flag,
    short* __restrict__ W2, float* __restrict__ bias2, short* __restrict__ owb,
    float* __restrict__ obf) {
  const int is32 = *flag;
  if (blockIdx.x < 192) {
    const int b = blockIdx.y;
    const int o = blockIdx.x * 4 + (threadIdx.x >> 6);
    const int lane = threadIdx.x & 63;
    const float f = (o % 192 < 64) ? CQ : 1.0f;
    float w[4], acc = 0.f;
#pragma unroll
    for (int k = 0; k < 4; k++) {
      int c = lane * 4 + k;
      w[k] = rd(qkv_w, (size_t)o * 256 + c, is32);
      acc += w[k] * shift[b * 256 + c];
      w[k] = w[k] * scale[b * 256 + c] * f;
    }
#pragma unroll
    for (int m = 1; m < 64; m <<= 1) acc += __shfl_xor(acc, m);
    if (lane == 0) bias2[b * 768 + o] = acc * f;
    uint2 u;
    u.x = pk2(w[0], w[1]);
    u.y = pk2(w[2], w[3]);
    *(uint2*)&W2[((size_t)b * 768 + o) * 256 + lane * 4] = u;
  } else if (blockIdx.y == 0) {
    int bx = blockIdx.x - 192;  // 0..63
    int i = (bx * 256 + threadIdx.x) * 4;
    uint2 u;
    u.x = pk2(rd(o_w, i, is32), rd(o_w, i + 1, is32));
    u.y = pk2(rd(o_w, i + 2, is32), rd(o_w, i + 3, is32));
    *(uint2*)&owb[i] = u;
    if (bx == 0) obf[threadIdx.x] = rd(o_b, threadIdx.x, is32);
  }
}

// ---------------------------------------------------------------------------
// QKV MFMA GEMM (r15/r17 version — proven): D[s][o] = xT·W2^T (+bias2).
// Block 128s x 64o, per-kt staging. seg 0 (q): row-major qT. seg 1 (k):
// fragment-major Kf. seg 2 (v): transpose + fragment-major Vf.
// ---------------------------------------------------------------------------
__global__ void __launch_bounds__(256) gemm_qkv_kernel(
    const short* __restrict__ xT, const short* __restrict__ W2,
    const float* __restrict__ bias2, short* __restrict__ qT,
    short* __restrict__ kF, short* __restrict__ vF) {
  __shared__ __align__(16) short lds[128 * 72 + 64 * 72];
  short* At = lds;             // xT tile [128 s][72]
  short* Bt = lds + 128 * 72;  // W2 tile [64 o][72]
  const int t = threadIdx.x;
  const int wave = t >> 6, lane = t & 63;
  const int ln = lane & 15, quad = lane >> 4;
  const int s0 = blockIdx.x * 128, by = blockIdx.y, b = blockIdx.z;
  const int o0 = by * 64;
  const short* xg = xT + ((size_t)b * 4096 + s0) * 256;
  const short* wg = W2 + ((size_t)b * 768 + o0) * 256;

  f32x4 acc[2][4];
#pragma unroll
  for (int mt = 0; mt < 2; mt++)
#pragma unroll
    for (int nt = 0; nt < 4; nt++) {
      f32x4 z = {0.f, 0.f, 0.f, 0.f};
      acc[mt][nt] = z;
    }

  for (int kt = 0; kt < 4; kt++) {
    __syncthreads();
    {
      int r = t >> 1, ch = t & 1;
#pragma unroll
      for (int j = 0; j < 4; j++)
        *(uint4*)&At[r * 72 + ch * 32 + j * 8] =
            *(const uint4*)&xg[(size_t)r * 256 + kt * 64 + ch * 32 + j * 8];
    }
    {
      int r = t >> 2, cq = t & 3;
#pragma unroll
      for (int j = 0; j < 2; j++)
        *(uint4*)&Bt[r * 72 + cq * 16 + j * 8] =
            *(const uint4*)&wg[(size_t)r * 256 + kt * 64 + cq * 16 + j * 8];
    }
    __syncthreads();
#pragma unroll
    for (int kd = 0; kd < 2; kd++) {
      short8 a[2], bb[4];
#pragma unroll
      for (int mt = 0; mt < 2; mt++)
        a[mt] = *(const short8*)&At[(wave * 32 + mt * 16 + ln) * 72 + kd * 32 +
                                    quad * 8];
#pragma unroll
      for (int nt = 0; nt < 4; nt++)
        bb[nt] = *(const short8*)&Bt[(nt * 16 + ln) * 72 + kd * 32 + quad * 8];
#pragma unroll
      for (int mt = 0; mt < 2; mt++)
#pragma unroll
        for (int nt = 0; nt < 4; nt++)
          acc[mt][nt] = __builtin_amdgcn_mfma_f32_16x16x32_bf16(
              a[mt], bb[nt], acc[mt][nt], 0, 0, 0);
    }
  }

  const int h = by / 3, seg = by % 3;
  const size_t bh = (size_t)b * 4 + h;
  __syncthreads();
  if (seg != 2) {
    short* T = At;  // [128 s][72] = [key_local][dh]
#pragma unroll
    for (int mt = 0; mt < 2; mt++)
#pragma unroll
      for (int nt = 0; nt < 4; nt++)
#pragma unroll
        for (int r = 0; r < 4; r++)
          T[(wave * 32 + mt * 16 + quad * 4 + r) * 72 + nt * 16 + ln] =
              (short)f2bf(acc[mt][nt][r] + bias2[b * 768 + o0 + nt * 16 + ln]);
    __syncthreads();
    if (seg == 0) {  // q: row-major
      short* dst = qT + (bh * 4096 + s0) * 64;
      int r = t >> 1, ch = t & 1;
#pragma unroll
      for (int j = 0; j < 2; j++)
        *(uint4*)&dst[r * 64 + ch * 32 + j * 8] =
            *(const uint4*)&T[r * 72 + ch * 32 + j * 8];
    } else {  // k: fragment-major
      short* dstf = kF + bh * 262144;
#pragma unroll
      for (int c = 0; c < 4; c++) {
        int cid = wave * 4 + c;
        int tile = cid >> 1, kd = cid & 1;
        short8 v =
            *(const short8*)&T[(tile * 16 + ln) * 72 + kd * 32 + quad * 8];
        *(short8*)&dstf[(size_t)((s0 / 16 + tile) * 2 + kd) * 512 + lane * 8] =
            v;
      }
    }
  } else {
    short* T2 = At;  // [64 dh][132 key_local]
#pragma unroll
    for (int mt = 0; mt < 2; mt++)
#pragma unroll
      for (int nt = 0; nt < 4; nt++) {
        float bv = bias2[b * 768 + o0 + nt * 16 + ln];
        uint2 u;
        u.x = pk2(acc[mt][nt][0] + bv, acc[mt][nt][1] + bv);
        u.y = pk2(acc[mt][nt][2] + bv, acc[mt][nt][3] + bv);
        *(uint2*)&T2[(nt * 16 + ln) * 132 + wave * 32 + mt * 16 + quad * 4] = u;
      }
    __syncthreads();
    short* dstf = vF + bh * 262144;
#pragma unroll
    for (int c = 0; c < 4; c++) {
      int cid = wave * 4 + c;
      int ktl = cid >> 3, rem = cid & 7, dt = rem >> 1, kc = rem & 1;
      short8 v = *(const short8*)&T2[(dt * 16 + ln) * 132 + ktl * 64 + kc * 32 +
                                     quad * 8];
      *(short8*)&dstf[(size_t)(((s0 / 64 + ktl) * 4 + dt) * 2 + kc) * 512 +
                      lane * 8] = v;
    }
  }
}

// ---------------------------------------------------------------------------
// Flash MFMA v15 (best measured: flash 64.7 us, total 160.5 us — r2).
// 32 q per WAVE (both 16-q tiles), split-K 4 across waves (each wave:
// 32 q x 1024 keys = 32 steps), K reg-dbuf + V single-buffer, 4-way
// combine in LDS. Evidence summary (r8-r15), recorded for posterity:
//  - v16 (K+V reg dbuf) & v17 (lifetime restructure): allocator refuses
//    >64 VGPR at launch_bounds(256,4); spills 99-117 MB scratch. DEAD END.
//  - v18 (LDS-DMA V + counted vmcnt + sched_barrier pinning): 267 MB
//    scratch, worse. Scheduling pinning aggravates allocation. DEAD END.
//  - v19 (LDS-shared K/V, 2x traffic cut, grid 512): correct, no spill,
//    but 71.8 us — occupancy halved (8 waves/CU) outweighs traffic cut.
//    PROVES v15 is NOT L2-BW-bound. DEAD END.
// v15 sits at a latency/issue-bound plateau (MfmaUtil 21, VALUBusy 29)
// that resists all source-level levers tried; it is the best verified
// configuration.
// ---------------------------------------------------------------------------
__global__ void __launch_bounds__(256, 4) flash_kernel(
    const short* __restrict__ qT, const short* __restrict__ kF,
    const short* __restrict__ vF, short* __restrict__ attT) {
  __shared__ float smem[8 * 64 * 20];  // [wave*2+tile][lane][20]: o(16)+l+pad
  const int t = threadIdx.x;
  const int wave = t >> 6, lane = t & 63;
  const int ln = lane & 15, quad = lane >> 4;
  const int L = blockIdx.x;
  const int bh = L & 7;  // XCD-pinned head stream
  const int b = bh >> 2, h = bh & 3;
  const int q0 = (L >> 3) * 32;

  const short* qg = qT + ((size_t)bh * 4096 + q0) * 64;
  // wave owns key quarter [wave*1024, wave*1024+1024)
  const short* kf = kF + (size_t)bh * 262144 + (size_t)wave * 65536;
  const short* vf = vF + (size_t)bh * 262144 + (size_t)wave * 65536;

  short8 qf[2][2];
#pragma unroll
  for (int tq = 0; tq < 2; tq++)
#pragma unroll
    for (int kd = 0; kd < 2; kd++)
      qf[tq][kd] = *(const short8*)&qg[(tq * 16 + ln) * 64 + kd * 32 + quad * 8];

  f32x4 ot[2][4];
#pragma unroll
  for (int tq = 0; tq < 2; tq++)
#pragma unroll
    for (int dt = 0; dt < 4; dt++) {
      f32x4 z = {0.f, 0.f, 0.f, 0.f};
      ot[tq][dt] = z;
    }
  float lres[2] = {0.f, 0.f};

  // 32-key step it (0..31): K tiles it*2+{0,1}; V tile64 it>>1, kc=it&1
  auto LOADK = [&](short8(&ka)[2][2], int it) {
    const short* kb = kf + (size_t)(it * 2) * 1024;
#pragma unroll
    for (int ct = 0; ct < 2; ct++)
#pragma unroll
      for (int kd = 0; kd < 2; kd++)
        ka[ct][kd] = *(const short8*)&kb[(ct * 2 + kd) * 512 + lane * 8];
  };
  auto LOADV = [&](short8(&va)[4], int it) {
    const short* vb = vf + (size_t)(it >> 1) * 4096;
    const int kc = it & 1;
#pragma unroll
    for (int dt = 0; dt < 4; dt++)
      va[dt] = *(const short8*)&vb[(dt * 2 + kc) * 512 + lane * 8];
  };

  auto STEP = [&](const short8(&ka)[2][2], const short8(&va)[4]) {
#pragma unroll
    for (int tq = 0; tq < 2; tq++) {
      f32x4 st[2];
#pragma unroll
      for (int ct = 0; ct < 2; ct++) {
        f32x4 z = {0.f, 0.f, 0.f, 0.f};
        st[ct] = z;
      }
#pragma unroll
      for (int kd = 0; kd < 2; kd++)
#pragma unroll
        for (int ct = 0; ct < 2; ct++)
          st[ct] = __builtin_amdgcn_mfma_f32_16x16x32_bf16(
              ka[ct][kd], qf[tq][kd], st[ct], 0, 0, 0);
      unsigned pk[2][2];
#pragma unroll
      for (int ct = 0; ct < 2; ct++) {
        float p0 = fexp2(st[ct][0]);
        float p1 = fexp2(st[ct][1]);
        float p2 = fexp2(st[ct][2]);
        float p3 = fexp2(st[ct][3]);
        lres[tq] += (p0 + p1) + (p2 + p3);
        pk[ct][0] = pk2t(p0, p1);
        pk[ct][1] = pk2t(p2, p3);
      }
      // P B-frag via 4 bpermutes within the query column
      const int tt = quad >> 1;
      const int qs = (quad & 1) * 2;
      union {
        unsigned u[4];
        short8 s;
      } bu;
      bu.u[0] = (unsigned)__shfl((int)pk[tt][0], qs * 16 + ln);
      bu.u[1] = (unsigned)__shfl((int)pk[tt][1], qs * 16 + ln);
      bu.u[2] = (unsigned)__shfl((int)pk[tt][0], (qs + 1) * 16 + ln);
      bu.u[3] = (unsigned)__shfl((int)pk[tt][1], (qs + 1) * 16 + ln);
#pragma unroll
      for (int dt = 0; dt < 4; dt++)
        ot[tq][dt] = __builtin_amdgcn_mfma_f32_16x16x32_bf16(
            va[dt], bu.s, ot[tq][dt], 0, 0, 0);
    }
  };

  short8 kaA[2][2], kaB[2][2], va[4];
  LOADK(kaA, 0);
#pragma unroll 1
  for (int it = 0; it < 32; it += 2) {
    LOADV(va, it);
    LOADK(kaB, it + 1);
    STEP(kaA, va);
    LOADV(va, it + 1);
    if (it < 30) LOADK(kaA, it + 2);
    STEP(kaB, va);
  }

  // per-tile: reduce l across quads; write partials to LDS
#pragma unroll
  for (int tq = 0; tq < 2; tq++) {
    float l = lres[tq];
    l += __shfl_xor(l, 16);
    l += __shfl_xor(l, 32);
    float* my = smem + ((wave * 2 + tq) * 64 + lane) * 20;
#pragma unroll
    for (int dt = 0; dt < 4; dt++) *(f32x4*)&my[dt * 4] = ot[tq][dt];
    my[16] = l;
  }
  __syncthreads();

  // 4-way combine: wave w handles tile (w&1), dh-half (w>>1).
  {
    const int tq = wave & 1;
    const float* p0 = smem + ((0 * 2 + tq) * 64 + lane) * 20;
    const float* p1 = smem + ((1 * 2 + tq) * 64 + lane) * 20;
    const float* p2 = smem + ((2 * 2 + tq) * 64 + lane) * 20;
    const float* p3 = smem + ((3 * 2 + tq) * 64 + lane) * 20;
    float lf = (p0[16] + p1[16]) + (p2[16] + p3[16]);
    float invl = 1.f / lf;
    int s = q0 + tq * 16 + ln;
    short* ap = attT + ((size_t)b * 4096 + s) * 256 + h * 64;
#pragma unroll
    for (int j = 0; j < 2; j++) {
      int dt = (wave >> 1) * 2 + j;
      f32x4 o0 = *(const f32x4*)&p0[dt * 4];
      f32x4 o1 = *(const f32x4*)&p1[dt * 4];
      f32x4 o2 = *(const f32x4*)&p2[dt * 4];
      f32x4 o3 = *(const f32x4*)&p3[dt * 4];
      uint2 u;
      u.x = pk2(((o0[0] + o1[0]) + (o2[0] + o3[0])) * invl,
                ((o0[1] + o1[1]) + (o2[1] + o3[1])) * invl);
      u.y = pk2(((o0[2] + o1[2]) + (o2[2] + o3[2])) * invl,
                ((o0[3] + o1[3]) + (o2[3] + o3[3])) * invl);
      *(uint2*)&ap[dt * 16 + quad * 4] = u;
    }
  }
}

// ---------------------------------------------------------------------------
// O-proj MFMA (r17 version — proven): 64s x 64o, per-kt staging, vectorized
// epilogue via fp32 LDS staging.
// ---------------------------------------------------------------------------
__global__ void __launch_bounds__(256) gemm_o_kernel(
    const short* __restrict__ owb, const short* __restrict__ attT,
    const float* __restrict__ obf, const void* __restrict__ xres,
    void* __restrict__ out, const int* __restrict__ flag) {
  __shared__ __align__(16) float ldsf[64 * 66];
  short* Bt = (short*)ldsf;  // attT tile [64 s][72]
  short* At = Bt + 64 * 72;  // o_w tile [64 o][72]
  const int t = threadIdx.x;
  const int wave = t >> 6, lane = t & 63;
  const int ln = lane & 15, quad = lane >> 4;
  const int s0 = blockIdx.x * 64, o0 = blockIdx.y * 64, b = blockIdx.z;
  const short* ag = attT + ((size_t)b * 4096 + s0) * 256;

  f32x4 acc[4];
#pragma unroll
  for (int mt = 0; mt < 4; mt++) {
    f32x4 z = {0.f, 0.f, 0.f, 0.f};
    acc[mt] = z;
  }

  for (int kt = 0; kt < 4; kt++) {
    __syncthreads();
    {
      int r = t >> 2, cq = t & 3;
#pragma unroll
      for (int j = 0; j < 2; j++)
        *(uint4*)&Bt[r * 72 + cq * 16 + j * 8] =
            *(const uint4*)&ag[(size_t)r * 256 + kt * 64 + cq * 16 + j * 8];
    }
    {
      int r = t >> 2, cq = t & 3;
#pragma unroll
      for (int j = 0; j < 2; j++)
        *(uint4*)&At[r * 72 + cq * 16 + j * 8] =
            *(const uint4*)&owb[(size_t)(o0 + r) * 256 + kt * 64 + cq * 16 +
                                j * 8];
    }
    __syncthreads();
#pragma unroll
    for (int kd = 0; kd < 2; kd++) {
      short8 a[4];
#pragma unroll
      for (int mt = 0; mt < 4; mt++)
        a[mt] = *(const short8*)&At[(mt * 16 + ln) * 72 + kd * 32 + quad * 8];
      short8 bb =
          *(const short8*)&Bt[(wave * 16 + ln) * 72 + kd * 32 + quad * 8];
#pragma unroll
      for (int mt = 0; mt < 4; mt++)
        acc[mt] = __builtin_amdgcn_mfma_f32_16x16x32_bf16(a[mt], bb, acc[mt],
                                                          0, 0, 0);
    }
  }

  __syncthreads();
#pragma unroll
  for (int mt = 0; mt < 4; mt++)
#pragma unroll
    for (int r = 0; r < 4; r++)
      ldsf[(mt * 16 + quad * 4 + r) * 66 + wave * 16 + ln] = acc[mt][r];
  __syncthreads();

  const int is32 = *flag;
#pragma unroll
  for (int j = 0; j < 4; j++) {
    int ol = j * 16 + (t >> 4);  // 0..63
    int sl = (t & 15) * 4;       // 0..60
    f32x4 v = *(const f32x4*)&ldsf[ol * 66 + sl];
    int o = o0 + ol;
    float bv = obf[o];
    size_t base = ((size_t)b * 256 + o) * 4096 + s0 + sl;
    if (is32) {
      const float4 rr = *(const float4*)&((const float*)xres)[base];
      float4 w;
      w.x = v[0] + bv + rr.x;
      w.y = v[1] + bv + rr.y;
      w.z = v[2] + bv + rr.z;
      w.w = v[3] + bv + rr.w;
      *(float4*)&((float*)out)[base] = w;
    } else {
      const uint2 rr = *(const uint2*)&((const bf16*)xres)[base];
      uint2 w;
      w.x = pk2(v[0] + bv + blo(rr.x), v[1] + bv + bhi(rr.x));
      w.y = pk2(v[2] + bv + blo(rr.y), v[3] + bv + bhi(rr.y));
      *(uint2*)&((bf16*)out)[base] = w;
    }
  }
}

// ---------------------------------------------------------------------------
extern "C" void kernel_launch(void* const* d_in, const int* in_sizes, int n_in,
                              void* d_out, int out_size, void* d_ws,
                              size_t ws_size, hipStream_t stream) {
  float* ws = (float*)d_ws;
  int* flag = (int*)ws;                  // @0
  float* scale = ws + 256;               // 512
  float* shift = ws + 768;               // 512
  float* bias2 = ws + 1280;              // 1536
  float* obf = ws + 2816;                // 256
  short* owb = (short*)(ws + 3072);      // 65536 shorts
  short* W2 = (short*)(ws + 35840);      // 393216 shorts
  short* xT = (short*)(ws + 232448);     // [b][4096][256] bf16
  short* qT = (short*)(ws + 1281024);    // [bh][4096][64] bf16 (row-major)
  short* kF = (short*)(ws + 2329600);    // [bh] frag-major K, 262144 ea
  short* vF = (short*)(ws + 3378176);    // [bh] frag-major V, 262144 ea
  short* attT = (short*)(ws + 4426752);  // [b][4096][256] bf16

  detect_kernel<<<1, 256, 0, stream>>>(d_in[0], flag);
  pre1_kernel<<<576, 256, 0, stream>>>(d_in[0], d_in[1], d_in[2], flag, scale,
                                       shift, xT);
  pre2_kernel<<<dim3(256, 2), 256, 0, stream>>>(d_in[3], d_in[4], d_in[5],
                                                scale, shift, flag, W2, bias2,
                                                owb, obf);
  gemm_qkv_kernel<<<dim3(32, 12, 2), 256, 0, stream>>>(xT, W2, bias2, qT, kF,
                                                       vF);
  flash_kernel<<<1024, 256, 0, stream>>>(qT, kF, vF, attT);
  gemm_o_kernel<<<dim3(64, 4, 2), 256, 0, stream>>>(owb, attT, obf, d_in[0],
                                                    d_out, flag);
}

// Round 20
// 152.276 us; speedup vs baseline: 1.5872x; 1.0619x over previous
//
#include <hip/hip_runtime.h>
#include <hip/hip_bf16.h>

typedef __hip_bfloat16 bf16;
typedef short short8 __attribute__((ext_vector_type(8)));  // 8 bf16 (4 VGPRs)
typedef float f32x4 __attribute__((ext_vector_type(4)));

__device__ __forceinline__ float b2f(bf16 v) { return __bfloat162float(v); }

// RNE fp32 -> bf16
__device__ __forceinline__ unsigned short f2bf(float x) {
  unsigned u = __builtin_bit_cast(unsigned, x);
  unsigned r = u + 0x7fffu + ((u >> 16) & 1u);
  return (unsigned short)(r >> 16);
}
__device__ __forceinline__ unsigned pk2(float a, float b) {
  return (unsigned)f2bf(a) | ((unsigned)f2bf(b) << 16);
}
// truncating pack via single v_perm_b32: dst = {a.hi16, b.hi16}
__device__ __forceinline__ unsigned pk2t(float a, float b) {
  return __builtin_amdgcn_perm(__builtin_bit_cast(unsigned, b),
                               __builtin_bit_cast(unsigned, a), 0x07060302u);
}
__device__ __forceinline__ float rd(const void* p, size_t i, int is32) {
  return is32 ? ((const float*)p)[i] : b2f(((const bf16*)p)[i]);
}
__device__ __forceinline__ float blo(unsigned w) {
  return __builtin_bit_cast(float, w << 16);
}
__device__ __forceinline__ float bhi(unsigned w) {
  return __builtin_bit_cast(float, w & 0xffff0000u);
}
// raw v_exp_f32 (scores bounded; no OCML special-casing)
__device__ __forceinline__ float fexp2(float x) {
  return __builtin_amdgcn_exp2f(x);
}

#define CQ 0.09016844005556022f  // (1/16) * log2(e), folded into q weights

// ---------------------------------------------------------------------------
// dtype detect: flag=1 fp32, flag=0 bf16 (see round-1 notes)
// ---------------------------------------------------------------------------
__global__ void __launch_bounds__(256) detect_kernel(const void* __restrict__ x,
                                                     int* __restrict__ flag) {
  __shared__ int cnt[256];
  const bf16* xb = (const bf16*)x;
  int c = 0;
  for (int i = threadIdx.x; i < 4096; i += 256) {
    float v = fabsf(b2f(xb[2 * i]));
    if (v >= 0.0009765625f && v <= 1024.0f) c++;
  }
  cnt[threadIdx.x] = c;
  __syncthreads();
  for (int off = 128; off > 0; off >>= 1) {
    if (threadIdx.x < off) cnt[threadIdx.x] += cnt[threadIdx.x + off];
    __syncthreads();
  }
  if (threadIdx.x == 0) *flag = (cnt[0] < 2048) ? 1 : 0;
}

// ---------------------------------------------------------------------------
// pre1: fused xt (blocks 0..511, vectorized loads) + gn_stats (blocks 512..575)
// ---------------------------------------------------------------------------
__global__ void __launch_bounds__(256) pre1_kernel(
    const void* __restrict__ x, const void* __restrict__ gn_w,
    const void* __restrict__ gn_b, const int* __restrict__ flag,
    float* __restrict__ scale, float* __restrict__ shift,
    short* __restrict__ xT) {
  __shared__ __align__(16) float F[64][72];
  const int t = threadIdx.x;
  const int is32 = *flag;
  if (blockIdx.x < 512) {
    const int bx = blockIdx.x;
    const int b = bx >> 8, rest = bx & 255;
    const int s0 = (rest >> 2) * 64, c0 = (rest & 3) * 64;
    if (is32) {
      const float* xp = (const float*)x;
#pragma unroll
      for (int k = 0; k < 4; k++) {
        int idx = k * 256 + t, cl = idx >> 4, c4 = idx & 15;
        float4 v = *(const float4*)&xp[(size_t)(b * 256 + c0 + cl) * 4096 + s0 +
                                       c4 * 4];
        *(float4*)&F[cl][c4 * 4] = v;
      }
    } else {
      const bf16* xp = (const bf16*)x;
#pragma unroll
      for (int k = 0; k < 2; k++) {
        int idx = k * 256 + t, cl = idx >> 3, c8 = idx & 7;
        uint4 u = *(const uint4*)&xp[(size_t)(b * 256 + c0 + cl) * 4096 + s0 +
                                     c8 * 8];
        float4 f0, f1;
        f0.x = blo(u.x); f0.y = bhi(u.x); f0.z = blo(u.y); f0.w = bhi(u.y);
        f1.x = blo(u.z); f1.y = bhi(u.z); f1.z = blo(u.w); f1.w = bhi(u.w);
        *(float4*)&F[cl][c8 * 8] = f0;
        *(float4*)&F[cl][c8 * 8 + 4] = f1;
      }
    }
    __syncthreads();
#pragma unroll
    for (int k = 0; k < 8; k++) {
      int idx = k * 256 + t;
      int sl = idx >> 5, c2 = (idx & 31) * 2;
      unsigned u = pk2(F[c2][sl], F[c2 + 1][sl]);
      *(unsigned*)&xT[((size_t)b * 4096 + s0 + sl) * 256 + c0 + c2] = u;
    }
  } else {
    const int idx0 = blockIdx.x - 512;
    const int b = idx0 >> 5, g = idx0 & 31;
    const size_t base = (size_t)(b * 256 + g * 8) * 4096;
    float s = 0.f, ss = 0.f;
    if (is32) {
      const float4* p = (const float4*)((const float*)x + base);
      for (int i = t; i < 8192; i += 256) {
        float4 v = p[i];
        s += (v.x + v.y) + (v.z + v.w);
        ss += v.x * v.x + v.y * v.y + v.z * v.z + v.w * v.w;
      }
    } else {
      const uint4* p = (const uint4*)((const bf16*)x + base);
      for (int i = t; i < 4096; i += 256) {
        uint4 u = p[i];
#pragma unroll
        for (int k = 0; k < 4; k++) {
          unsigned w = (&u.x)[k];
          float lo = blo(w), hi = bhi(w);
          s += lo + hi;
          ss += lo * lo + hi * hi;
        }
      }
    }
    float* rs = &F[0][0];
    float* rq = rs + 256;
    rs[t] = s;
    rq[t] = ss;
    __syncthreads();
    for (int off = 128; off > 0; off >>= 1) {
      if (t < off) {
        rs[t] += rs[t + off];
        rq[t] += rq[t + off];
      }
      __syncthreads();
    }
    if (t < 8) {
      const float inv_n = 1.f / 32768.f;
      float mean = rs[0] * inv_n;
      float var = rq[0] * inv_n - mean * mean;
      float rstd = rsqrtf(var + 1e-5f);
      int c = g * 8 + t;
      float sc = rd(gn_w, c, is32) * rstd;
      scale[b * 256 + c] = sc;
      shift[b * 256 + c] = rd(gn_b, c, is32) - mean * sc;
    }
  }
}

// ---------------------------------------------------------------------------
// pre2: fused prep_w (bx<192) + conv_o (bx>=192, by==0).
// ---------------------------------------------------------------------------
__global__ void __launch_bounds__(256) pre2_kernel(
    const void* __restrict__ qkv_w, const void* __restrict__ o_w,
    const void* __restrict__ o_b, const float* __restrict__ scale,
    const float* __restrict__ shift, const int* __restrict__ flag,
    short* __restrict__ W2, float* __restrict__ bias2, short* __restrict__ owb,
    float* __restrict__ obf) {
  const int is32 = *flag;
  if (blockIdx.x < 192) {
    const int b = blockIdx.y;
    const int o = blockIdx.x * 4 + (threadIdx.x >> 6);
    const int lane = threadIdx.x & 63;
    const float f = (o % 192 < 64) ? CQ : 1.0f;
    float w[4], acc = 0.f;
#pragma unroll
    for (int k = 0; k < 4; k++) {
      int c = lane * 4 + k;
      w[k] = rd(qkv_w, (size_t)o * 256 + c, is32);
      acc += w[k] * shift[b * 256 + c];
      w[k] = w[k] * scale[b * 256 + c] * f;
    }
#pragma unroll
    for (int m = 1; m < 64; m <<= 1) acc += __shfl_xor(acc, m);
    if (lane == 0) bias2[b * 768 + o] = acc * f;
    uint2 u;
    u.x = pk2(w[0], w[1]);
    u.y = pk2(w[2], w[3]);
    *(uint2*)&W2[((size_t)b * 768 + o) * 256 + lane * 4] = u;
  } else if (blockIdx.y == 0) {
    int bx = blockIdx.x - 192;  // 0..63
    int i = (bx * 256 + threadIdx.x) * 4;
    uint2 u;
    u.x = pk2(rd(o_w, i, is32), rd(o_w, i + 1, is32));
    u.y = pk2(rd(o_w, i + 2, is32), rd(o_w, i + 3, is32));
    *(uint2*)&owb[i] = u;
    if (bx == 0) obf[threadIdx.x] = rd(o_b, threadIdx.x, is32);
  }
}

// ---------------------------------------------------------------------------
// QKV MFMA GEMM (r15/r17 version — proven): D[s][o] = xT·W2^T (+bias2).
// Block 128s x 64o, per-kt staging. seg 0 (q): row-major qT. seg 1 (k):
// fragment-major Kf. seg 2 (v): transpose + fragment-major Vf.
// ---------------------------------------------------------------------------
__global__ void __launch_bounds__(256) gemm_qkv_kernel(
    const short* __restrict__ xT, const short* __restrict__ W2,
    const float* __restrict__ bias2, short* __restrict__ qT,
    short* __restrict__ kF, short* __restrict__ vF) {
  __shared__ __align__(16) short lds[128 * 72 + 64 * 72];
  short* At = lds;             // xT tile [128 s][72]
  short* Bt = lds + 128 * 72;  // W2 tile [64 o][72]
  const int t = threadIdx.x;
  const int wave = t >> 6, lane = t & 63;
  const int ln = lane & 15, quad = lane >> 4;
  const int s0 = blockIdx.x * 128, by = blockIdx.y, b = blockIdx.z;
  const int o0 = by * 64;
  const short* xg = xT + ((size_t)b * 4096 + s0) * 256;
  const short* wg = W2 + ((size_t)b * 768 + o0) * 256;

  f32x4 acc[2][4];
#pragma unroll
  for (int mt = 0; mt < 2; mt++)
#pragma unroll
    for (int nt = 0; nt < 4; nt++) {
      f32x4 z = {0.f, 0.f, 0.f, 0.f};
      acc[mt][nt] = z;
    }

  for (int kt = 0; kt < 4; kt++) {
    __syncthreads();
    {
      int r = t >> 1, ch = t & 1;
#pragma unroll
      for (int j = 0; j < 4; j++)
        *(uint4*)&At[r * 72 + ch * 32 + j * 8] =
            *(const uint4*)&xg[(size_t)r * 256 + kt * 64 + ch * 32 + j * 8];
    }
    {
      int r = t >> 2, cq = t & 3;
#pragma unroll
      for (int j = 0; j < 2; j++)
        *(uint4*)&Bt[r * 72 + cq * 16 + j * 8] =
            *(const uint4*)&wg[(size_t)r * 256 + kt * 64 + cq * 16 + j * 8];
    }
    __syncthreads();
#pragma unroll
    for (int kd = 0; kd < 2; kd++) {
      short8 a[2], bb[4];
#pragma unroll
      for (int mt = 0; mt < 2; mt++)
        a[mt] = *(const short8*)&At[(wave * 32 + mt * 16 + ln) * 72 + kd * 32 +
                                    quad * 8];
#pragma unroll
      for (int nt = 0; nt < 4; nt++)
        bb[nt] = *(const short8*)&Bt[(nt * 16 + ln) * 72 + kd * 32 + quad * 8];
#pragma unroll
      for (int mt = 0; mt < 2; mt++)
#pragma unroll
        for (int nt = 0; nt < 4; nt++)
          acc[mt][nt] = __builtin_amdgcn_mfma_f32_16x16x32_bf16(
              a[mt], bb[nt], acc[mt][nt], 0, 0, 0);
    }
  }

  const int h = by / 3, seg = by % 3;
  const size_t bh = (size_t)b * 4 + h;
  __syncthreads();
  if (seg != 2) {
    short* T = At;  // [128 s][72] = [key_local][dh]
#pragma unroll
    for (int mt = 0; mt < 2; mt++)
#pragma unroll
      for (int nt = 0; nt < 4; nt++)
#pragma unroll
        for (int r = 0; r < 4; r++)
          T[(wave * 32 + mt * 16 + quad * 4 + r) * 72 + nt * 16 + ln] =
              (short)f2bf(acc[mt][nt][r] + bias2[b * 768 + o0 + nt * 16 + ln]);
    __syncthreads();
    if (seg == 0) {  // q: row-major
      short* dst = qT + (bh * 4096 + s0) * 64;
      int r = t >> 1, ch = t & 1;
#pragma unroll
      for (int j = 0; j < 2; j++)
        *(uint4*)&dst[r * 64 + ch * 32 + j * 8] =
            *(const uint4*)&T[r * 72 + ch * 32 + j * 8];
    } else {  // k: fragment-major
      short* dstf = kF + bh * 262144;
#pragma unroll
      for (int c = 0; c < 4; c++) {
        int cid = wave * 4 + c;
        int tile = cid >> 1, kd = cid & 1;
        short8 v =
            *(const short8*)&T[(tile * 16 + ln) * 72 + kd * 32 + quad * 8];
        *(short8*)&dstf[(size_t)((s0 / 16 + tile) * 2 + kd) * 512 + lane * 8] =
            v;
      }
    }
  } else {
    short* T2 = At;  // [64 dh][132 key_local]
#pragma unroll
    for (int mt = 0; mt < 2; mt++)
#pragma unroll
      for (int nt = 0; nt < 4; nt++) {
        float bv = bias2[b * 768 + o0 + nt * 16 + ln];
        uint2 u;
        u.x = pk2(acc[mt][nt][0] + bv, acc[mt][nt][1] + bv);
        u.y = pk2(acc[mt][nt][2] + bv, acc[mt][nt][3] + bv);
        *(uint2*)&T2[(nt * 16 + ln) * 132 + wave * 32 + mt * 16 + quad * 4] = u;
      }
    __syncthreads();
    short* dstf = vF + bh * 262144;
#pragma unroll
    for (int c = 0; c < 4; c++) {
      int cid = wave * 4 + c;
      int ktl = cid >> 3, rem = cid & 7, dt = rem >> 1, kc = rem & 1;
      short8 v = *(const short8*)&T2[(dt * 16 + ln) * 132 + ktl * 64 + kc * 32 +
                                     quad * 8];
      *(short8*)&dstf[(size_t)(((s0 / 64 + ktl) * 4 + dt) * 2 + kc) * 512 +
                      lane * 8] = v;
    }
  }
}

// ---------------------------------------------------------------------------
// Flash MFMA v20: v16's FULL K+V double-buffer schedule (2-step prefetch
// depth) at __launch_bounds__(256, 3) — the one untested cell in the
// {prefetch depth} x {register budget} matrix. v16 failed ONLY because
// (256,4) capped the allocator at the 64-VGPR tier (spill 99 MB); at
// (256,3) the budget is ~168 VGPR, the ~96-VGPR demand fits with margin.
// Cost: occupancy 16 -> 12 waves/CU (-25%); v19 calibrates -50% occupancy
// at ~-11%, so expect ~-5% from TLP vs +20-30% if the latency theory
// (every K/V buffer >= 2 STEPs in flight) is right.
// Pre-committed: (a) WRITE_SIZE inflated -> allocator ignores budget,
// terminal revert to v15. (b) WRITE normal, dur >= 68 -> occupancy loss
// wins, terminal revert. (c) dur < 64 -> new best.
// ---------------------------------------------------------------------------
__global__ void __launch_bounds__(256, 3) flash_kernel(
    const short* __restrict__ qT, const short* __restrict__ kF,
    const short* __restrict__ vF, short* __restrict__ attT) {
  __shared__ float smem[8 * 64 * 20];  // [wave*2+tile][lane][20]: o(16)+l+pad
  const int t = threadIdx.x;
  const int wave = t >> 6, lane = t & 63;
  const int ln = lane & 15, quad = lane >> 4;
  const int L = blockIdx.x;
  const int bh = L & 7;  // XCD-pinned head stream
  const int b = bh >> 2, h = bh & 3;
  const int q0 = (L >> 3) * 32;

  const short* qg = qT + ((size_t)bh * 4096 + q0) * 64;
  // wave owns key quarter [wave*1024, wave*1024+1024)
  const short* kf = kF + (size_t)bh * 262144 + (size_t)wave * 65536;
  const short* vf = vF + (size_t)bh * 262144 + (size_t)wave * 65536;

  short8 qf[2][2];
#pragma unroll
  for (int tq = 0; tq < 2; tq++)
#pragma unroll
    for (int kd = 0; kd < 2; kd++)
      qf[tq][kd] = *(const short8*)&qg[(tq * 16 + ln) * 64 + kd * 32 + quad * 8];

  f32x4 ot[2][4];
#pragma unroll
  for (int tq = 0; tq < 2; tq++)
#pragma unroll
    for (int dt = 0; dt < 4; dt++) {
      f32x4 z = {0.f, 0.f, 0.f, 0.f};
      ot[tq][dt] = z;
    }
  float lres[2] = {0.f, 0.f};

  // 32-key step it (0..31): K tiles it*2+{0,1}; V tile64 it>>1, kc=it&1
  auto LOADK = [&](short8(&ka)[2][2], int it) {
    const short* kb = kf + (size_t)(it * 2) * 1024;
#pragma unroll
    for (int ct = 0; ct < 2; ct++)
#pragma unroll
      for (int kd = 0; kd < 2; kd++)
        ka[ct][kd] = *(const short8*)&kb[(ct * 2 + kd) * 512 + lane * 8];
  };
  auto LOADV = [&](short8(&va)[4], int it) {
    const short* vb = vf + (size_t)(it >> 1) * 4096;
    const int kc = it & 1;
#pragma unroll
    for (int dt = 0; dt < 4; dt++)
      va[dt] = *(const short8*)&vb[(dt * 2 + kc) * 512 + lane * 8];
  };

  auto STEP = [&](const short8(&ka)[2][2], const short8(&va)[4]) {
#pragma unroll
    for (int tq = 0; tq < 2; tq++) {
      f32x4 st[2];
#pragma unroll
      for (int ct = 0; ct < 2; ct++) {
        f32x4 z = {0.f, 0.f, 0.f, 0.f};
        st[ct] = z;
      }
#pragma unroll
      for (int kd = 0; kd < 2; kd++)
#pragma unroll
        for (int ct = 0; ct < 2; ct++)
          st[ct] = __builtin_amdgcn_mfma_f32_16x16x32_bf16(
              ka[ct][kd], qf[tq][kd], st[ct], 0, 0, 0);
      unsigned pk[2][2];
#pragma unroll
      for (int ct = 0; ct < 2; ct++) {
        float p0 = fexp2(st[ct][0]);
        float p1 = fexp2(st[ct][1]);
        float p2 = fexp2(st[ct][2]);
        float p3 = fexp2(st[ct][3]);
        lres[tq] += (p0 + p1) + (p2 + p3);
        pk[ct][0] = pk2t(p0, p1);
        pk[ct][1] = pk2t(p2, p3);
      }
      // P B-frag via 4 bpermutes within the query column
      const int tt = quad >> 1;
      const int qs = (quad & 1) * 2;
      union {
        unsigned u[4];
        short8 s;
      } bu;
      bu.u[0] = (unsigned)__shfl((int)pk[tt][0], qs * 16 + ln);
      bu.u[1] = (unsigned)__shfl((int)pk[tt][1], qs * 16 + ln);
      bu.u[2] = (unsigned)__shfl((int)pk[tt][0], (qs + 1) * 16 + ln);
      bu.u[3] = (unsigned)__shfl((int)pk[tt][1], (qs + 1) * 16 + ln);
#pragma unroll
      for (int dt = 0; dt < 4; dt++)
        ot[tq][dt] = __builtin_amdgcn_mfma_f32_16x16x32_bf16(
            va[dt], bu.s, ot[tq][dt], 0, 0, 0);
    }
  };

  short8 kaA[2][2], kaB[2][2], vaA[4], vaB[4];
  LOADK(kaA, 0);
  LOADV(vaA, 0);
  LOADK(kaB, 1);
  LOADV(vaB, 1);
#pragma unroll 1
  for (int it = 0; it < 32; it += 2) {
    STEP(kaA, vaA);
    if (it < 30) {
      LOADK(kaA, it + 2);
      LOADV(vaA, it + 2);
    }
    STEP(kaB, vaB);
    if (it < 30) {
      LOADK(kaB, it + 3);
      LOADV(vaB, it + 3);
    }
  }

  // per-tile: reduce l across quads; write partials to LDS
#pragma unroll
  for (int tq = 0; tq < 2; tq++) {
    float l = lres[tq];
    l += __shfl_xor(l, 16);
    l += __shfl_xor(l, 32);
    float* my = smem + ((wave * 2 + tq) * 64 + lane) * 20;
#pragma unroll
    for (int dt = 0; dt < 4; dt++) *(f32x4*)&my[dt * 4] = ot[tq][dt];
    my[16] = l;
  }
  __syncthreads();

  // 4-way combine: wave w handles tile (w&1), dh-half (w>>1).
  {
    const int tq = wave & 1;
    const float* p0 = smem + ((0 * 2 + tq) * 64 + lane) * 20;
    const float* p1 = smem + ((1 * 2 + tq) * 64 + lane) * 20;
    const float* p2 = smem + ((2 * 2 + tq) * 64 + lane) * 20;
    const float* p3 = smem + ((3 * 2 + tq) * 64 + lane) * 20;
    float lf = (p0[16] + p1[16]) + (p2[16] + p3[16]);
    float invl = 1.f / lf;
    int s = q0 + tq * 16 + ln;
    short* ap = attT + ((size_t)b * 4096 + s) * 256 + h * 64;
#pragma unroll
    for (int j = 0; j < 2; j++) {
      int dt = (wave >> 1) * 2 + j;
      f32x4 o0 = *(const f32x4*)&p0[dt * 4];
      f32x4 o1 = *(const f32x4*)&p1[dt * 4];
      f32x4 o2 = *(const f32x4*)&p2[dt * 4];
      f32x4 o3 = *(const f32x4*)&p3[dt * 4];
      uint2 u;
      u.x = pk2(((o0[0] + o1[0]) + (o2[0] + o3[0])) * invl,
                ((o0[1] + o1[1]) + (o2[1] + o3[1])) * invl);
      u.y = pk2(((o0[2] + o1[2]) + (o2[2] + o3[2])) * invl,
                ((o0[3] + o1[3]) + (o2[3] + o3[3])) * invl);
      *(uint2*)&ap[dt * 16 + quad * 4] = u;
    }
  }
}

// ---------------------------------------------------------------------------
// O-proj MFMA (r17 version — proven): 64s x 64o, per-kt staging, vectorized
// epilogue via fp32 LDS staging.
// ---------------------------------------------------------------------------
__global__ void __launch_bounds__(256) gemm_o_kernel(
    const short* __restrict__ owb, const short* __restrict__ attT,
    const float* __restrict__ obf, const void* __restrict__ xres,
    void* __restrict__ out, const int* __restrict__ flag) {
  __shared__ __align__(16) float ldsf[64 * 66];
  short* Bt = (short*)ldsf;  // attT tile [64 s][72]
  short* At = Bt + 64 * 72;  // o_w tile [64 o][72]
  const int t = threadIdx.x;
  const int wave = t >> 6, lane = t & 63;
  const int ln = lane & 15, quad = lane >> 4;
  const int s0 = blockIdx.x * 64, o0 = blockIdx.y * 64, b = blockIdx.z;
  const short* ag = attT + ((size_t)b * 4096 + s0) * 256;

  f32x4 acc[4];
#pragma unroll
  for (int mt = 0; mt < 4; mt++) {
    f32x4 z = {0.f, 0.f, 0.f, 0.f};
    acc[mt] = z;
  }

  for (int kt = 0; kt < 4; kt++) {
    __syncthreads();
    {
      int r = t >> 2, cq = t & 3;
#pragma unroll
      for (int j = 0; j < 2; j++)
        *(uint4*)&Bt[r * 72 + cq * 16 + j * 8] =
            *(const uint4*)&ag[(size_t)r * 256 + kt * 64 + cq * 16 + j * 8];
    }
    {
      int r = t >> 2, cq = t & 3;
#pragma unroll
      for (int j = 0; j < 2; j++)
        *(uint4*)&At[r * 72 + cq * 16 + j * 8] =
            *(const uint4*)&owb[(size_t)(o0 + r) * 256 + kt * 64 + cq * 16 +
                                j * 8];
    }
    __syncthreads();
#pragma unroll
    for (int kd = 0; kd < 2; kd++) {
      short8 a[4];
#pragma unroll
      for (int mt = 0; mt < 4; mt++)
        a[mt] = *(const short8*)&At[(mt * 16 + ln) * 72 + kd * 32 + quad * 8];
      short8 bb =
          *(const short8*)&Bt[(wave * 16 + ln) * 72 + kd * 32 + quad * 8];
#pragma unroll
      for (int mt = 0; mt < 4; mt++)
        acc[mt] = __builtin_amdgcn_mfma_f32_16x16x32_bf16(a[mt], bb, acc[mt],
                                                          0, 0, 0);
    }
  }

  __syncthreads();
#pragma unroll
  for (int mt = 0; mt < 4; mt++)
#pragma unroll
    for (int r = 0; r < 4; r++)
      ldsf[(mt * 16 + quad * 4 + r) * 66 + wave * 16 + ln] = acc[mt][r];
  __syncthreads();

  const int is32 = *flag;
#pragma unroll
  for (int j = 0; j < 4; j++) {
    int ol = j * 16 + (t >> 4);  // 0..63
    int sl = (t & 15) * 4;       // 0..60
    f32x4 v = *(const f32x4*)&ldsf[ol * 66 + sl];
    int o = o0 + ol;
    float bv = obf[o];
    size_t base = ((size_t)b * 256 + o) * 4096 + s0 + sl;
    if (is32) {
      const float4 rr = *(const float4*)&((const float*)xres)[base];
      float4 w;
      w.x = v[0] + bv + rr.x;
      w.y = v[1] + bv + rr.y;
      w.z = v[2] + bv + rr.z;
      w.w = v[3] + bv + rr.w;
      *(float4*)&((float*)out)[base] = w;
    } else {
      const uint2 rr = *(const uint2*)&((const bf16*)xres)[base];
      uint2 w;
      w.x = pk2(v[0] + bv + blo(rr.x), v[1] + bv + bhi(rr.x));
      w.y = pk2(v[2] + bv + blo(rr.y), v[3] + bv + bhi(rr.y));
      *(uint2*)&((bf16*)out)[base] = w;
    }
  }
}

// ---------------------------------------------------------------------------
extern "C" void kernel_launch(void* const* d_in, const int* in_sizes, int n_in,
                              void* d_out, int out_size, void* d_ws,
                              size_t ws_size, hipStream_t stream) {
  float* ws = (float*)d_ws;
  int* flag = (int*)ws;                  // @0
  float* scale = ws + 256;               // 512
  float* shift = ws + 768;               // 512
  float* bias2 = ws + 1280;              // 1536
  float* obf = ws + 2816;                // 256
  short* owb = (short*)(ws + 3072);      // 65536 shorts
  short* W2 = (short*)(ws + 35840);      // 393216 shorts
  short* xT = (short*)(ws + 232448);     // [b][4096][256] bf16
  short* qT = (short*)(ws + 1281024);    // [bh][4096][64] bf16 (row-major)
  short* kF = (short*)(ws + 2329600);    // [bh] frag-major K, 262144 ea
  short* vF = (short*)(ws + 3378176);    // [bh] frag-major V, 262144 ea
  short* attT = (short*)(ws + 4426752);  // [b][4096][256] bf16

  detect_kernel<<<1, 256, 0, stream>>>(d_in[0], flag);
  pre1_kernel<<<576, 256, 0, stream>>>(d_in[0], d_in[1], d_in[2], flag, scale,
                                       shift, xT);
  pre2_kernel<<<dim3(256, 2), 256, 0, stream>>>(d_in[3], d_in[4], d_in[5],
                                                scale, shift, flag, W2, bias2,
                                                owb, obf);
  gemm_qkv_kernel<<<dim3(32, 12, 2), 256, 0, stream>>>(xT, W2, bias2, qT, kF,
                                                       vF);
  flash_kernel<<<1024, 256, 0, stream>>>(qT, kF, vF, attT);
  gemm_o_kernel<<<dim3(64, 4, 2), 256, 0, stream>>>(owb, attT, obf, d_in[0],
                                                    d_out, flag);
}

// Round 23
// 152.092 us; speedup vs baseline: 1.5891x; 1.0012x over previous
//
#include <hip/hip_runtime.h>
#include <hip/hip_bf16.h>

typedef __hip_bfloat16 bf16;
typedef short short8 __attribute__((ext_vector_type(8)));  // 8 bf16 (4 VGPRs)
typedef float f32x4 __attribute__((ext_vector_type(4)));

__device__ __forceinline__ float b2f(bf16 v) { return __bfloat162float(v); }

// RNE fp32 -> bf16
__device__ __forceinline__ unsigned short f2bf(float x) {
  unsigned u = __builtin_bit_cast(unsigned, x);
  unsigned r = u + 0x7fffu + ((u >> 16) & 1u);
  return (unsigned short)(r >> 16);
}
__device__ __forceinline__ unsigned pk2(float a, float b) {
  return (unsigned)f2bf(a) | ((unsigned)f2bf(b) << 16);
}
// truncating pack via single v_perm_b32: dst = {a.hi16, b.hi16}
__device__ __forceinline__ unsigned pk2t(float a, float b) {
  return __builtin_amdgcn_perm(__builtin_bit_cast(unsigned, b),
                               __builtin_bit_cast(unsigned, a), 0x07060302u);
}
__device__ __forceinline__ float rd(const void* p, size_t i, int is32) {
  return is32 ? ((const float*)p)[i] : b2f(((const bf16*)p)[i]);
}
__device__ __forceinline__ float blo(unsigned w) {
  return __builtin_bit_cast(float, w << 16);
}
__device__ __forceinline__ float bhi(unsigned w) {
  return __builtin_bit_cast(float, w & 0xffff0000u);
}
// raw v_exp_f32 (scores bounded; no OCML special-casing)
__device__ __forceinline__ float fexp2(float x) {
  return __builtin_amdgcn_exp2f(x);
}

#define CQ 0.09016844005556022f  // (1/16) * log2(e), folded into q weights

// ---------------------------------------------------------------------------
// dtype detect: flag=1 fp32, flag=0 bf16 (see round-1 notes)
// ---------------------------------------------------------------------------
__global__ void __launch_bounds__(256) detect_kernel(const void* __restrict__ x,
                                                     int* __restrict__ flag) {
  __shared__ int cnt[256];
  const bf16* xb = (const bf16*)x;
  int c = 0;
  for (int i = threadIdx.x; i < 4096; i += 256) {
    float v = fabsf(b2f(xb[2 * i]));
    if (v >= 0.0009765625f && v <= 1024.0f) c++;
  }
  cnt[threadIdx.x] = c;
  __syncthreads();
  for (int off = 128; off > 0; off >>= 1) {
    if (threadIdx.x < off) cnt[threadIdx.x] += cnt[threadIdx.x + off];
    __syncthreads();
  }
  if (threadIdx.x == 0) *flag = (cnt[0] < 2048) ? 1 : 0;
}

// ---------------------------------------------------------------------------
// pre1: fused xt (blocks 0..511, vectorized loads) + gn_stats (blocks 512..575)
// ---------------------------------------------------------------------------
__global__ void __launch_bounds__(256) pre1_kernel(
    const void* __restrict__ x, const void* __restrict__ gn_w,
    const void* __restrict__ gn_b, const int* __restrict__ flag,
    float* __restrict__ scale, float* __restrict__ shift,
    short* __restrict__ xT) {
  __shared__ __align__(16) float F[64][72];
  const int t = threadIdx.x;
  const int is32 = *flag;
  if (blockIdx.x < 512) {
    const int bx = blockIdx.x;
    const int b = bx >> 8, rest = bx & 255;
    const int s0 = (rest >> 2) * 64, c0 = (rest & 3) * 64;
    if (is32) {
      const float* xp = (const float*)x;
#pragma unroll
      for (int k = 0; k < 4; k++) {
        int idx = k * 256 + t, cl = idx >> 4, c4 = idx & 15;
        float4 v = *(const float4*)&xp[(size_t)(b * 256 + c0 + cl) * 4096 + s0 +
                                       c4 * 4];
        *(float4*)&F[cl][c4 * 4] = v;
      }
    } else {
      const bf16* xp = (const bf16*)x;
#pragma unroll
      for (int k = 0; k < 2; k++) {
        int idx = k * 256 + t, cl = idx >> 3, c8 = idx & 7;
        uint4 u = *(const uint4*)&xp[(size_t)(b * 256 + c0 + cl) * 4096 + s0 +
                                     c8 * 8];
        float4 f0, f1;
        f0.x = blo(u.x); f0.y = bhi(u.x); f0.z = blo(u.y); f0.w = bhi(u.y);
        f1.x = blo(u.z); f1.y = bhi(u.z); f1.z = blo(u.w); f1.w = bhi(u.w);
        *(float4*)&F[cl][c8 * 8] = f0;
        *(float4*)&F[cl][c8 * 8 + 4] = f1;
      }
    }
    __syncthreads();
#pragma unroll
    for (int k = 0; k < 8; k++) {
      int idx = k * 256 + t;
      int sl = idx >> 5, c2 = (idx & 31) * 2;
      unsigned u = pk2(F[c2][sl], F[c2 + 1][sl]);
      *(unsigned*)&xT[((size_t)b * 4096 + s0 + sl) * 256 + c0 + c2] = u;
    }
  } else {
    const int idx0 = blockIdx.x - 512;
    const int b = idx0 >> 5, g = idx0 & 31;
    const size_t base = (size_t)(b * 256 + g * 8) * 4096;
    float s = 0.f, ss = 0.f;
    if (is32) {
      const float4* p = (const float4*)((const float*)x + base);
      for (int i = t; i < 8192; i += 256) {
        float4 v = p[i];
        s += (v.x + v.y) + (v.z + v.w);
        ss += v.x * v.x + v.y * v.y + v.z * v.z + v.w * v.w;
      }
    } else {
      const uint4* p = (const uint4*)((const bf16*)x + base);
      for (int i = t; i < 4096; i += 256) {
        uint4 u = p[i];
#pragma unroll
        for (int k = 0; k < 4; k++) {
          unsigned w = (&u.x)[k];
          float lo = blo(w), hi = bhi(w);
          s += lo + hi;
          ss += lo * lo + hi * hi;
        }
      }
    }
    float* rs = &F[0][0];
    float* rq = rs + 256;
    rs[t] = s;
    rq[t] = ss;
    __syncthreads();
    for (int off = 128; off > 0; off >>= 1) {
      if (t < off) {
        rs[t] += rs[t + off];
        rq[t] += rq[t + off];
      }
      __syncthreads();
    }
    if (t < 8) {
      const float inv_n = 1.f / 32768.f;
      float mean = rs[0] * inv_n;
      float var = rq[0] * inv_n - mean * mean;
      float rstd = rsqrtf(var + 1e-5f);
      int c = g * 8 + t;
      float sc = rd(gn_w, c, is32) * rstd;
      scale[b * 256 + c] = sc;
      shift[b * 256 + c] = rd(gn_b, c, is32) - mean * sc;
    }
  }
}

// ---------------------------------------------------------------------------
// pre2: fused prep_w (bx<192) + conv_o (bx>=192, by==0).
// ---------------------------------------------------------------------------
__global__ void __launch_bounds__(256) pre2_kernel(
    const void* __restrict__ qkv_w, const void* __restrict__ o_w,
    const void* __restrict__ o_b, const float* __restrict__ scale,
    const float* __restrict__ shift, const int* __restrict__ flag,
    short* __restrict__ W2, float* __restrict__ bias2, short* __restrict__ owb,
    float* __restrict__ obf) {
  const int is32 = *flag;
  if (blockIdx.x < 192) {
    const int b = blockIdx.y;
    const int o = blockIdx.x * 4 + (threadIdx.x >> 6);
    const int lane = threadIdx.x & 63;
    const float f = (o % 192 < 64) ? CQ : 1.0f;
    float w[4], acc = 0.f;
#pragma unroll
    for (int k = 0; k < 4; k++) {
      int c = lane * 4 + k;
      w[k] = rd(qkv_w, (size_t)o * 256 + c, is32);
      acc += w[k] * shift[b * 256 + c];
      w[k] = w[k] * scale[b * 256 + c] * f;
    }
#pragma unroll
    for (int m = 1; m < 64; m <<= 1) acc += __shfl_xor(acc, m);
    if (lane == 0) bias2[b * 768 + o] = acc * f;
    uint2 u;
    u.x = pk2(w[0], w[1]);
    u.y = pk2(w[2], w[3]);
    *(uint2*)&W2[((size_t)b * 768 + o) * 256 + lane * 4] = u;
  } else if (blockIdx.y == 0) {
    int bx = blockIdx.x - 192;  // 0..63
    int i = (bx * 256 + threadIdx.x) * 4;
    uint2 u;
    u.x = pk2(rd(o_w, i, is32), rd(o_w, i + 1, is32));
    u.y = pk2(rd(o_w, i + 2, is32), rd(o_w, i + 3, is32));
    *(uint2*)&owb[i] = u;
    if (bx == 0) obf[threadIdx.x] = rd(o_b, threadIdx.x, is32);
  }
}

// ---------------------------------------------------------------------------
// QKV MFMA GEMM (r15/r17 version — proven): D[s][o] = xT·W2^T (+bias2).
// Block 128s x 64o, per-kt staging. seg 0 (q): row-major qT. seg 1 (k):
// fragment-major Kf. seg 2 (v): transpose + fragment-major Vf.
// ---------------------------------------------------------------------------
__global__ void __launch_bounds__(256) gemm_qkv_kernel(
    const short* __restrict__ xT, const short* __restrict__ W2,
    const float* __restrict__ bias2, short* __restrict__ qT,
    short* __restrict__ kF, short* __restrict__ vF) {
  __shared__ __align__(16) short lds[128 * 72 + 64 * 72];
  short* At = lds;             // xT tile [128 s][72]
  short* Bt = lds + 128 * 72;  // W2 tile [64 o][72]
  const int t = threadIdx.x;
  const int wave = t >> 6, lane = t & 63;
  const int ln = lane & 15, quad = lane >> 4;
  const int s0 = blockIdx.x * 128, by = blockIdx.y, b = blockIdx.z;
  const int o0 = by * 64;
  const short* xg = xT + ((size_t)b * 4096 + s0) * 256;
  const short* wg = W2 + ((size_t)b * 768 + o0) * 256;

  f32x4 acc[2][4];
#pragma unroll
  for (int mt = 0; mt < 2; mt++)
#pragma unroll
    for (int nt = 0; nt < 4; nt++) {
      f32x4 z = {0.f, 0.f, 0.f, 0.f};
      acc[mt][nt] = z;
    }

  for (int kt = 0; kt < 4; kt++) {
    __syncthreads();
    {
      int r = t >> 1, ch = t & 1;
#pragma unroll
      for (int j = 0; j < 4; j++)
        *(uint4*)&At[r * 72 + ch * 32 + j * 8] =
            *(const uint4*)&xg[(size_t)r * 256 + kt * 64 + ch * 32 + j * 8];
    }
    {
      int r = t >> 2, cq = t & 3;
#pragma unroll
      for (int j = 0; j < 2; j++)
        *(uint4*)&Bt[r * 72 + cq * 16 + j * 8] =
            *(const uint4*)&wg[(size_t)r * 256 + kt * 64 + cq * 16 + j * 8];
    }
    __syncthreads();
#pragma unroll
    for (int kd = 0; kd < 2; kd++) {
      short8 a[2], bb[4];
#pragma unroll
      for (int mt = 0; mt < 2; mt++)
        a[mt] = *(const short8*)&At[(wave * 32 + mt * 16 + ln) * 72 + kd * 32 +
                                    quad * 8];
#pragma unroll
      for (int nt = 0; nt < 4; nt++)
        bb[nt] = *(const short8*)&Bt[(nt * 16 + ln) * 72 + kd * 32 + quad * 8];
#pragma unroll
      for (int mt = 0; mt < 2; mt++)
#pragma unroll
        for (int nt = 0; nt < 4; nt++)
          acc[mt][nt] = __builtin_amdgcn_mfma_f32_16x16x32_bf16(
              a[mt], bb[nt], acc[mt][nt], 0, 0, 0);
    }
  }

  const int h = by / 3, seg = by % 3;
  const size_t bh = (size_t)b * 4 + h;
  __syncthreads();
  if (seg != 2) {
    short* T = At;  // [128 s][72] = [key_local][dh]
#pragma unroll
    for (int mt = 0; mt < 2; mt++)
#pragma unroll
      for (int nt = 0; nt < 4; nt++)
#pragma unroll
        for (int r = 0; r < 4; r++)
          T[(wave * 32 + mt * 16 + quad * 4 + r) * 72 + nt * 16 + ln] =
              (short)f2bf(acc[mt][nt][r] + bias2[b * 768 + o0 + nt * 16 + ln]);
    __syncthreads();
    if (seg == 0) {  // q: row-major
      short* dst = qT + (bh * 4096 + s0) * 64;
      int r = t >> 1, ch = t & 1;
#pragma unroll
      for (int j = 0; j < 2; j++)
        *(uint4*)&dst[r * 64 + ch * 32 + j * 8] =
            *(const uint4*)&T[r * 72 + ch * 32 + j * 8];
    } else {  // k: fragment-major
      short* dstf = kF + bh * 262144;
#pragma unroll
      for (int c = 0; c < 4; c++) {
        int cid = wave * 4 + c;
        int tile = cid >> 1, kd = cid & 1;
        short8 v =
            *(const short8*)&T[(tile * 16 + ln) * 72 + kd * 32 + quad * 8];
        *(short8*)&dstf[(size_t)((s0 / 16 + tile) * 2 + kd) * 512 + lane * 8] =
            v;
      }
    }
  } else {
    short* T2 = At;  // [64 dh][132 key_local]
#pragma unroll
    for (int mt = 0; mt < 2; mt++)
#pragma unroll
      for (int nt = 0; nt < 4; nt++) {
        float bv = bias2[b * 768 + o0 + nt * 16 + ln];
        uint2 u;
        u.x = pk2(acc[mt][nt][0] + bv, acc[mt][nt][1] + bv);
        u.y = pk2(acc[mt][nt][2] + bv, acc[mt][nt][3] + bv);
        *(uint2*)&T2[(nt * 16 + ln) * 132 + wave * 32 + mt * 16 + quad * 4] = u;
      }
    __syncthreads();
    short* dstf = vF + bh * 262144;
#pragma unroll
    for (int c = 0; c < 4; c++) {
      int cid = wave * 4 + c;
      int ktl = cid >> 3, rem = cid & 7, dt = rem >> 1, kc = rem & 1;
      short8 v = *(const short8*)&T2[(dt * 16 + ln) * 132 + ktl * 64 + kc * 32 +
                                     quad * 8];
      *(short8*)&dstf[(size_t)(((s0 / 64 + ktl) * 4 + dt) * 2 + kc) * 512 +
                      lane * 8] = v;
    }
  }
}

// ---------------------------------------------------------------------------
// Flash MFMA v21: v20 (K+V reg dbuf, 2-step prefetch, launch_bounds(256,3)
// — NEW BEST, flash 52.7 us / total 152.3, VGPR 80, no spill) + LDS shrink
// 40960 -> 34816 via the v18 combine layout (part[16]/lane + separate
// lsum; correctness-verified r14). Rationale: VGPR 80 <= 128 permits
// 4 waves/SIMD; LDS 40960 x 4 = 163840 = exactly 160 KB with ZERO margin —
// any runtime LDS reservation drops blocks/CU to 3 (measured occupancy
// 22.7% vs v15's 33%). 34816 B guarantees 4 blocks/CU.
// Pre-committed: (a) dur improves -> occupancy theory confirmed, keep.
// (b) neutral -> keep (no downside); remaining idle is dependency chains.
// (c) regression/spill -> revert to v20 as terminal.
// ---------------------------------------------------------------------------
__global__ void __launch_bounds__(256, 3) flash_kernel(
    const short* __restrict__ qT, const short* __restrict__ kF,
    const short* __restrict__ vF, short* __restrict__ attT) {
  // part[w2t][lane][16] f32 (32 KB) + lsum[w2t][lane] (2 KB) = 34816 B
  __shared__ __align__(16) char smem_raw[34816];
  float* part = (float*)smem_raw;
  float* lsum = (float*)(smem_raw + 32768);
  const int t = threadIdx.x;
  const int wave = t >> 6, lane = t & 63;
  const int ln = lane & 15, quad = lane >> 4;
  const int L = blockIdx.x;
  const int bh = L & 7;  // XCD-pinned head stream
  const int b = bh >> 2, h = bh & 3;
  const int q0 = (L >> 3) * 32;

  const short* qg = qT + ((size_t)bh * 4096 + q0) * 64;
  // wave owns key quarter [wave*1024, wave*1024+1024)
  const short* kf = kF + (size_t)bh * 262144 + (size_t)wave * 65536;
  const short* vf = vF + (size_t)bh * 262144 + (size_t)wave * 65536;

  short8 qf[2][2];
#pragma unroll
  for (int tq = 0; tq < 2; tq++)
#pragma unroll
    for (int kd = 0; kd < 2; kd++)
      qf[tq][kd] = *(const short8*)&qg[(tq * 16 + ln) * 64 + kd * 32 + quad * 8];

  f32x4 ot[2][4];
#pragma unroll
  for (int tq = 0; tq < 2; tq++)
#pragma unroll
    for (int dt = 0; dt < 4; dt++) {
      f32x4 z = {0.f, 0.f, 0.f, 0.f};
      ot[tq][dt] = z;
    }
  float lres[2] = {0.f, 0.f};

  // 32-key step it (0..31): K tiles it*2+{0,1}; V tile64 it>>1, kc=it&1
  auto LOADK = [&](short8(&ka)[2][2], int it) {
    const short* kb = kf + (size_t)(it * 2) * 1024;
#pragma unroll
    for (int ct = 0; ct < 2; ct++)
#pragma unroll
      for (int kd = 0; kd < 2; kd++)
        ka[ct][kd] = *(const short8*)&kb[(ct * 2 + kd) * 512 + lane * 8];
  };
  auto LOADV = [&](short8(&va)[4], int it) {
    const short* vb = vf + (size_t)(it >> 1) * 4096;
    const int kc = it & 1;
#pragma unroll
    for (int dt = 0; dt < 4; dt++)
      va[dt] = *(const short8*)&vb[(dt * 2 + kc) * 512 + lane * 8];
  };

  auto STEP = [&](const short8(&ka)[2][2], const short8(&va)[4]) {
#pragma unroll
    for (int tq = 0; tq < 2; tq++) {
      f32x4 st[2];
#pragma unroll
      for (int ct = 0; ct < 2; ct++) {
        f32x4 z = {0.f, 0.f, 0.f, 0.f};
        st[ct] = z;
      }
#pragma unroll
      for (int kd = 0; kd < 2; kd++)
#pragma unroll
        for (int ct = 0; ct < 2; ct++)
          st[ct] = __builtin_amdgcn_mfma_f32_16x16x32_bf16(
              ka[ct][kd], qf[tq][kd], st[ct], 0, 0, 0);
      unsigned pk[2][2];
#pragma unroll
      for (int ct = 0; ct < 2; ct++) {
        float p0 = fexp2(st[ct][0]);
        float p1 = fexp2(st[ct][1]);
        float p2 = fexp2(st[ct][2]);
        float p3 = fexp2(st[ct][3]);
        lres[tq] += (p0 + p1) + (p2 + p3);
        pk[ct][0] = pk2t(p0, p1);
        pk[ct][1] = pk2t(p2, p3);
      }
      // P B-frag via 4 bpermutes within the query column
      const int tt = quad >> 1;
      const int qs = (quad & 1) * 2;
      union {
        unsigned u[4];
        short8 s;
      } bu;
      bu.u[0] = (unsigned)__shfl((int)pk[tt][0], qs * 16 + ln);
      bu.u[1] = (unsigned)__shfl((int)pk[tt][1], qs * 16 + ln);
      bu.u[2] = (unsigned)__shfl((int)pk[tt][0], (qs + 1) * 16 + ln);
      bu.u[3] = (unsigned)__shfl((int)pk[tt][1], (qs + 1) * 16 + ln);
#pragma unroll
      for (int dt = 0; dt < 4; dt++)
        ot[tq][dt] = __builtin_amdgcn_mfma_f32_16x16x32_bf16(
            va[dt], bu.s, ot[tq][dt], 0, 0, 0);
    }
  };

  short8 kaA[2][2], kaB[2][2], vaA[4], vaB[4];
  LOADK(kaA, 0);
  LOADV(vaA, 0);
  LOADK(kaB, 1);
  LOADV(vaB, 1);
#pragma unroll 1
  for (int it = 0; it < 32; it += 2) {
    STEP(kaA, vaA);
    if (it < 30) {
      LOADK(kaA, it + 2);
      LOADV(vaA, it + 2);
    }
    STEP(kaB, vaB);
    if (it < 30) {
      LOADK(kaB, it + 3);
      LOADV(vaB, it + 3);
    }
  }

  // per-tile: reduce l across quads; write partials to LDS
#pragma unroll
  for (int tq = 0; tq < 2; tq++) {
    float l = lres[tq];
    l += __shfl_xor(l, 16);
    l += __shfl_xor(l, 32);
    float* my = part + ((wave * 2 + tq) * 64 + lane) * 16;
#pragma unroll
    for (int dt = 0; dt < 4; dt++) *(f32x4*)&my[dt * 4] = ot[tq][dt];
    lsum[(wave * 2 + tq) * 64 + lane] = l;
  }
  __syncthreads();

  // 4-way combine: wave w handles tile (w&1), dh-half (w>>1).
  {
    const int tq = wave & 1;
    const float* p0 = part + ((0 + tq) * 64 + lane) * 16;
    const float* p1 = part + ((2 + tq) * 64 + lane) * 16;
    const float* p2 = part + ((4 + tq) * 64 + lane) * 16;
    const float* p3 = part + ((6 + tq) * 64 + lane) * 16;
    float lf = (lsum[(0 + tq) * 64 + lane] + lsum[(2 + tq) * 64 + lane]) +
               (lsum[(4 + tq) * 64 + lane] + lsum[(6 + tq) * 64 + lane]);
    float invl = 1.f / lf;
    int s = q0 + tq * 16 + ln;
    short* ap = attT + ((size_t)b * 4096 + s) * 256 + h * 64;
#pragma unroll
    for (int j = 0; j < 2; j++) {
      int dt = (wave >> 1) * 2 + j;
      f32x4 o0 = *(const f32x4*)&p0[dt * 4];
      f32x4 o1 = *(const f32x4*)&p1[dt * 4];
      f32x4 o2 = *(const f32x4*)&p2[dt * 4];
      f32x4 o3 = *(const f32x4*)&p3[dt * 4];
      uint2 u;
      u.x = pk2(((o0[0] + o1[0]) + (o2[0] + o3[0])) * invl,
                ((o0[1] + o1[1]) + (o2[1] + o3[1])) * invl);
      u.y = pk2(((o0[2] + o1[2]) + (o2[2] + o3[2])) * invl,
                ((o0[3] + o1[3]) + (o2[3] + o3[3])) * invl);
      *(uint2*)&ap[dt * 16 + quad * 4] = u;
    }
  }
}

// ---------------------------------------------------------------------------
// O-proj MFMA (r17 version — proven): 64s x 64o, per-kt staging, vectorized
// epilogue via fp32 LDS staging.
// ---------------------------------------------------------------------------
__global__ void __launch_bounds__(256) gemm_o_kernel(
    const short* __restrict__ owb, const short* __restrict__ attT,
    const float* __restrict__ obf, const void* __restrict__ xres,
    void* __restrict__ out, const int* __restrict__ flag) {
  __shared__ __align__(16) float ldsf[64 * 66];
  short* Bt = (short*)ldsf;  // attT tile [64 s][72]
  short* At = Bt + 64 * 72;  // o_w tile [64 o][72]
  const int t = threadIdx.x;
  const int wave = t >> 6, lane = t & 63;
  const int ln = lane & 15, quad = lane >> 4;
  const int s0 = blockIdx.x * 64, o0 = blockIdx.y * 64, b = blockIdx.z;
  const short* ag = attT + ((size_t)b * 4096 + s0) * 256;

  f32x4 acc[4];
#pragma unroll
  for (int mt = 0; mt < 4; mt++) {
    f32x4 z = {0.f, 0.f, 0.f, 0.f};
    acc[mt] = z;
  }

  for (int kt = 0; kt < 4; kt++) {
    __syncthreads();
    {
      int r = t >> 2, cq = t & 3;
#pragma unroll
      for (int j = 0; j < 2; j++)
        *(uint4*)&Bt[r * 72 + cq * 16 + j * 8] =
            *(const uint4*)&ag[(size_t)r * 256 + kt * 64 + cq * 16 + j * 8];
    }
    {
      int r = t >> 2, cq = t & 3;
#pragma unroll
      for (int j = 0; j < 2; j++)
        *(uint4*)&At[r * 72 + cq * 16 + j * 8] =
            *(const uint4*)&owb[(size_t)(o0 + r) * 256 + kt * 64 + cq * 16 +
                                j * 8];
    }
    __syncthreads();
#pragma unroll
    for (int kd = 0; kd < 2; kd++) {
      short8 a[4];
#pragma unroll
      for (int mt = 0; mt < 4; mt++)
        a[mt] = *(const short8*)&At[(mt * 16 + ln) * 72 + kd * 32 + quad * 8];
      short8 bb =
          *(const short8*)&Bt[(wave * 16 + ln) * 72 + kd * 32 + quad * 8];
#pragma unroll
      for (int mt = 0; mt < 4; mt++)
        acc[mt] = __builtin_amdgcn_mfma_f32_16x16x32_bf16(a[mt], bb, acc[mt],
                                                          0, 0, 0);
    }
  }

  __syncthreads();
#pragma unroll
  for (int mt = 0; mt < 4; mt++)
#pragma unroll
    for (int r = 0; r < 4; r++)
      ldsf[(mt * 16 + quad * 4 + r) * 66 + wave * 16 + ln] = acc[mt][r];
  __syncthreads();

  const int is32 = *flag;
#pragma unroll
  for (int j = 0; j < 4; j++) {
    int ol = j * 16 + (t >> 4);  // 0..63
    int sl = (t & 15) * 4;       // 0..60
    f32x4 v = *(const f32x4*)&ldsf[ol * 66 + sl];
    int o = o0 + ol;
    float bv = obf[o];
    size_t base = ((size_t)b * 256 + o) * 4096 + s0 + sl;
    if (is32) {
      const float4 rr = *(const float4*)&((const float*)xres)[base];
      float4 w;
      w.x = v[0] + bv + rr.x;
      w.y = v[1] + bv + rr.y;
      w.z = v[2] + bv + rr.z;
      w.w = v[3] + bv + rr.w;
      *(float4*)&((float*)out)[base] = w;
    } else {
      const uint2 rr = *(const uint2*)&((const bf16*)xres)[base];
      uint2 w;
      w.x = pk2(v[0] + bv + blo(rr.x), v[1] + bv + bhi(rr.x));
      w.y = pk2(v[2] + bv + blo(rr.y), v[3] + bv + bhi(rr.y));
      *(uint2*)&((bf16*)out)[base] = w;
    }
  }
}

// ---------------------------------------------------------------------------
extern "C" void kernel_launch(void* const* d_in, const int* in_sizes, int n_in,
                              void* d_out, int out_size, void* d_ws,
                              size_t ws_size, hipStream_t stream) {
  float* ws = (float*)d_ws;
  int* flag = (int*)ws;                  // @0
  float* scale = ws + 256;               // 512
  float* shift = ws + 768;               // 512
  float* bias2 = ws + 1280;              // 1536
  float* obf = ws + 2816;                // 256
  short* owb = (short*)(ws + 3072);      // 65536 shorts
  short* W2 = (short*)(ws + 35840);      // 393216 shorts
  short* xT = (short*)(ws + 232448);     // [b][4096][256] bf16
  short* qT = (short*)(ws + 1281024);    // [bh][4096][64] bf16 (row-major)
  short* kF = (short*)(ws + 2329600);    // [bh] frag-major K, 262144 ea
  short* vF = (short*)(ws + 3378176);    // [bh] frag-major V, 262144 ea
  short* attT = (short*)(ws + 4426752);  // [b][4096][256] bf16

  detect_kernel<<<1, 256, 0, stream>>>(d_in[0], flag);
  pre1_kernel<<<576, 256, 0, stream>>>(d_in[0], d_in[1], d_in[2], flag, scale,
                                       shift, xT);
  pre2_kernel<<<dim3(256, 2), 256, 0, stream>>>(d_in[3], d_in[4], d_in[5],
                                                scale, shift, flag, W2, bias2,
                                                owb, obf);
  gemm_qkv_kernel<<<dim3(32, 12, 2), 256, 0, stream>>>(xT, W2, bias2, qT, kF,
                                                       vF);
  flash_kernel<<<1024, 256, 0, stream>>>(qT, kF, vF, attT);
  gemm_o_kernel<<<dim3(64, 4, 2), 256, 0, stream>>>(owb, attT, obf, d_in[0],
                                                    d_out, flag);
}